// Round 3
// baseline (702.281 us; speedup 1.0000x reference)
//
#include <hip/hip_runtime.h>

#define DEVINL __device__ __forceinline__

constexpr int B_ = 8, N_ = 1024, D_ = 64, H_ = 4, QV_ = 32;
constexpr int C_ = 129, K_ = 16, M_ = 4096;
constexpr int CP = 132;              // padded C (multiple of 4)
constexpr int NG = B_ * N_;          // 8192 nodes total

// ---- workspace layout (float offsets) ----
constexpr size_t o_Wvp   = 0;                                   // H*C*CP padded Wv
constexpr size_t o_q     = o_Wvp + (size_t)H_ * C_ * CP;        // H*NG*K
constexpr size_t o_k     = o_q   + (size_t)H_ * NG * K_;        // H*NG*K
constexpr size_t o_v     = o_k   + (size_t)H_ * NG * K_;        // H*NG*CP (padded)
constexpr size_t o_hp    = o_v   + (size_t)H_ * NG * CP;        // M*516 attn_cat
constexpr size_t o_cpost = o_hp  + (size_t)M_ * 516;            // M*CP
constexpr size_t o_W1p   = o_cpost + (size_t)M_ * CP;           // 516*CP
constexpr size_t o_W2p   = o_W1p + (size_t)516 * CP;            // 129*CP
constexpr size_t o_lsum  = o_W2p + (size_t)C_ * CP;             // H*M
// aliases (lifetimes disjoint)
constexpr size_t o_pru = o_v;      // 8*M*64  (after attn, v dead)
constexpr size_t o_cin = o_q;      // M*CP    (after attn, q+k dead)
constexpr size_t o_pc  = o_hp;     // 8*M*64  (after mlp, hp dead)

DEVINL float4 ld4(const float* p) { return *reinterpret_cast<const float4*>(p); }
DEVINL float2 ld2(const float* p) { return *reinterpret_cast<const float2*>(p); }
DEVINL void st4(float* p, float4 v) { *reinterpret_cast<float4*>(p) = v; }
DEVINL void st2(float* p, float2 v) { *reinterpret_cast<float2*>(p) = v; }

// ---------------- K0: pad Wv,W1,W2 into [*][CP] layouts ----------------
__global__ void k_prep(const float* __restrict__ Wv, float* __restrict__ Wvp,
                       const float* __restrict__ W1, float* __restrict__ W1p,
                       const float* __restrict__ W2, float* __restrict__ W2p) {
    int idx = blockIdx.x * 256 + threadIdx.x;
    const int totV = H_ * C_ * CP;   // 68112
    const int tot1 = 516 * CP;       // 68112
    const int tot2 = C_ * CP;        // 17028
    if (idx < totV) {
        int hh = idx / (C_ * CP); int rem = idx - hh * C_ * CP;
        int cc = rem / CP;        int o  = rem - cc * CP;
        Wvp[idx] = (o < C_) ? Wv[(hh * C_ + cc) * C_ + o] : 0.f;
    } else if (idx < totV + tot1) {
        int r = (idx - totV) / CP, o = (idx - totV) - ((idx - totV) / CP) * CP;
        W1p[r * CP + o] = (o < C_) ? W1[r * C_ + o] : 0.f;
    } else if (idx < totV + tot1 + tot2) {
        int j = idx - totV - tot1;
        int r = j / CP, o = j - r * CP;
        W2p[r * CP + o] = (o < C_) ? W2[r * C_ + o] : 0.f;
    }
}

// ---------------- Kz: zero hp + lsum ----------------
__global__ void k_zero(float* __restrict__ hp, float* __restrict__ lsum) {
    int idx = blockIdx.x * 256 + threadIdx.x;
    if (idx < M_ * 516) hp[idx] = 0.f;
    if (idx < H_ * M_) lsum[idx] = 0.f;
}

// ---------------- K1: combined -> q,k (all nodes), v (padded); 32-row tiles ----------------
__global__ __launch_bounds__(256) void k_qkv(
    const float* __restrict__ x, const float* __restrict__ h,
    const float* __restrict__ Wq, const float* __restrict__ bq,
    const float* __restrict__ Wk, const float* __restrict__ bk,
    const float* __restrict__ Wvp, const float* __restrict__ bv,
    float* __restrict__ qo, float* __restrict__ ko, float* __restrict__ vo) {
    __shared__ float Cs[32][CP];
    const int t = threadIdx.x;
    const int g0 = blockIdx.x * 32;
    const int hh = blockIdx.y;
    for (int idx = t; idx < 32 * C_; idx += 256) {
        int r = idx / C_, cc = idx - r * C_;
        int g = g0 + r; int b = g >> 10, n = g & (N_ - 1);
        Cs[r][cc] = (cc < 65) ? x[(b * N_ + n) * 65 + cc]
                              : h[(b * N_ + n) * D_ + (cc - 65)];
    }
    __syncthreads();
    // q (waves 0,1) or k (waves 2,3): r = (t&127)>>2, kquad = (t&3)*4
    {
        const int r = (t & 127) >> 2, kb = (t & 3) * 4;
        const float* W = (t < 128) ? Wq : Wk;
        const float* bb = (t < 128) ? bq : bk;
        float a[4];
#pragma unroll
        for (int j = 0; j < 4; ++j) a[j] = bb[hh * K_ + kb + j];
        for (int cc = 0; cc < C_; ++cc) {
            float s = Cs[r][cc];
            float4 w = ld4(&W[(size_t)(hh * C_ + cc) * K_ + kb]);
            a[0] += s * w.x; a[1] += s * w.y; a[2] += s * w.z; a[3] += s * w.w;
        }
        float* dst = (t < 128) ? qo : ko;
        st4(&dst[(size_t)(hh * NG + g0 + r) * K_ + kb], make_float4(a[0], a[1], a[2], a[3]));
    }
    // v main cols 0..127
    for (int jj = 0; jj < 4; ++jj) {
        int idx = t + 256 * jj;
        int r = idx >> 5, o4 = (idx & 31) * 4;
        float a0 = bv[hh * C_ + o4 + 0], a1 = bv[hh * C_ + o4 + 1],
              a2 = bv[hh * C_ + o4 + 2], a3 = bv[hh * C_ + o4 + 3];
        for (int cc = 0; cc < C_; ++cc) {
            float s = Cs[r][cc];
            float4 w = ld4(&Wvp[(size_t)(hh * C_ + cc) * CP + o4]);
            a0 += s * w.x; a1 += s * w.y; a2 += s * w.z; a3 += s * w.w;
        }
        st4(&vo[(size_t)(hh * NG + g0 + r) * CP + o4], make_float4(a0, a1, a2, a3));
    }
    // v col 128 + zero pads
    if (t < 32) {
        int r = t;
        float a = bv[hh * C_ + 128];
        for (int cc = 0; cc < C_; ++cc) a += Cs[r][cc] * Wvp[(size_t)(hh * C_ + cc) * CP + 128];
        float* vp = &vo[(size_t)(hh * NG + g0 + r) * CP];
        vp[128] = a; vp[129] = 0.f; vp[130] = 0.f; vp[131] = 0.f;
    }
}

// ---------------- K3: attention, col-split x4, atomic partial accumulate ----------------
// grid (M/32, H, 4); each block: 8 col-tiles of 32 cols.
__global__ __launch_bounds__(256) void k_attn(
    const float* __restrict__ qg, const float* __restrict__ kg, const float* __restrict__ vg,
    const int* __restrict__ adj, const int* __restrict__ nodes_b, const int* __restrict__ nodes_n,
    float* __restrict__ hp, float* __restrict__ lsum) {
    __shared__ float Ks[32][20];
    __shared__ float Vs[32][132];
    __shared__ float Pt[32][36];
    __shared__ int Nrow[32];
    const int t = threadIdx.x;
    const int m0 = blockIdx.x * 32;
    const int hh = blockIdx.y;
    const int z = blockIdx.z;
    const int b = nodes_b[m0];
    if (t < 32) Nrow[t] = nodes_n[m0 + t];
    __syncthreads();
    const int sr = t >> 3, sc0 = t & 7;              // score mapping: 32 rows x 8 lanes
    float qreg[16];
    {
        const float* qp = &qg[(size_t)(hh * NG + b * N_ + Nrow[sr]) * K_];
#pragma unroll
        for (int w = 0; w < 16; w += 4) {
            float4 qq = ld4(qp + w);
            qreg[w] = qq.x; qreg[w + 1] = qq.y; qreg[w + 2] = qq.z; qreg[w + 3] = qq.w;
        }
    }
    const int prg4 = (t >> 5) * 4, ptc4 = (t & 31) * 4;   // PV: 8 rowgroups x 32 colgroups
    float acc[4][4] = {{0.f}};
    float accX = 0.f;
    const int xr = (t < 128) ? (t >> 2) : 0, xo = t & 3;
    float lpart = 0.f;
    const int* adjrow = &adj[(size_t)Nrow[sr] * N_];
    for (int ct = 0; ct < 8; ++ct) {
        const int c0 = (z * 8 + ct) * 32;
        __syncthreads();
        if (t < 128) { // stage K tile (32 rows x 16)
            int row = t >> 2, k4 = (t & 3) * 4;
            st4(&Ks[row][k4], ld4(&kg[(size_t)(hh * NG + b * N_ + c0 + row) * K_ + k4]));
        }
        for (int idx = t; idx < 32 * 33; idx += 256) { // stage V tile (32 rows x 132)
            int row = idx / 33, c4 = (idx - row * 33) * 4;
            st4(&Vs[row][c4], ld4(&vg[(size_t)(hh * NG + b * N_ + c0 + row) * CP + c4]));
        }
        __syncthreads();
#pragma unroll
        for (int j = 0; j < 4; ++j) {
            int c = sc0 + 8 * j;
            float4 ka = ld4(&Ks[c][0]), kb4 = ld4(&Ks[c][4]), kc4 = ld4(&Ks[c][8]), kd = ld4(&Ks[c][12]);
            float dot = qreg[0]*ka.x + qreg[1]*ka.y + qreg[2]*ka.z + qreg[3]*ka.w
                      + qreg[4]*kb4.x + qreg[5]*kb4.y + qreg[6]*kb4.z + qreg[7]*kb4.w
                      + qreg[8]*kc4.x + qreg[9]*kc4.y + qreg[10]*kc4.z + qreg[11]*kc4.w
                      + qreg[12]*kd.x + qreg[13]*kd.y + qreg[14]*kd.z + qreg[15]*kd.w;
            float s = dot * 0.25f;
            s = (s >= 0.f) ? s : 0.2f * s;
            float p = adjrow[c0 + c] ? __expf(s) : 0.f;
            lpart += p;
            Pt[c][sr] = p;
        }
        __syncthreads();
#pragma unroll 4
        for (int c = 0; c < 32; ++c) {
            float4 pv = ld4(&Pt[c][prg4]);
            float4 vv = ld4(&Vs[c][ptc4]);
            const float* pp = (const float*)&pv;
            const float* vp = (const float*)&vv;
#pragma unroll
            for (int ri = 0; ri < 4; ++ri)
#pragma unroll
                for (int oi = 0; oi < 4; ++oi) acc[ri][oi] += pp[ri] * vp[oi];
            if (t < 128) accX += Pt[c][xr] * Vs[c][128 + xo];
        }
    }
    lpart += __shfl_xor(lpart, 1);
    lpart += __shfl_xor(lpart, 2);
    lpart += __shfl_xor(lpart, 4);
    if (sc0 == 0) atomicAdd(&lsum[hh * M_ + m0 + sr], lpart);
#pragma unroll
    for (int ri = 0; ri < 4; ++ri) {
        float* op = &hp[(size_t)(m0 + prg4 + ri) * 516 + hh * C_ + ptc4];
#pragma unroll
        for (int oi = 0; oi < 4; ++oi) atomicAdd(op + oi, acc[ri][oi]);
    }
    if (t < 128 && xo == 0)
        atomicAdd(&hp[(size_t)(m0 + xr) * 516 + hh * C_ + 128], accX);
}

// ---------------- Kn: normalize hp by lsum ----------------
__global__ void k_norm(float* __restrict__ hp, const float* __restrict__ lsum) {
    int idx = blockIdx.x * 256 + threadIdx.x;
    if (idx >= M_ * 516) return;
    int m = idx / 516, j = idx - m * 516;
    int hh = j / C_;
    float l = lsum[hh * M_ + m];
    hp[idx] = (l > 0.f) ? hp[idx] / l : 0.f;
}

// ---------------- K4: node MLP + skip -> cpost[M][CP]; 16-row tiles ----------------
__global__ __launch_bounds__(256) void k_mlp(
    const float* __restrict__ hp,
    const float* __restrict__ W1p, const float* __restrict__ b1,
    const float* __restrict__ W2p, const float* __restrict__ b2,
    const float* __restrict__ x, const float* __restrict__ h,
    const int* __restrict__ nb, const int* __restrict__ nn,
    float* __restrict__ cpost) {
    __shared__ float T[CP][20];
    const int t = threadIdx.x;
    const int m0 = blockIdx.x * 16;
    const int r0 = (t >> 5) * 2;          // 8 rowgroups * 2 = 16 rows
    const int o0 = (t & 31) * 4;          // 32 colgroups * 4 = 128 cols
    const int rX = (t < 64) ? (t >> 2) : 0;  // extra col path: 16 rows x 4 cols
    const int oX = 128 + (t & 3);
    float acc[2][4] = {{0.f}};
    float accX = 0.f;
    // ---- GEMM1: hidden = relu(hp @ W1 + b1), k = 516 in 4 chunks ----
    for (int chunk = 0; chunk < 4; ++chunk) {
        const int kc = chunk * 132;
        const int csz = (chunk < 3) ? 132 : 120;
        __syncthreads();
        for (int idx = t; idx < 16 * 33; idx += 256) {
            int r = idx / 33, i4 = (idx - r * 33) * 4;
            if (i4 + 3 < csz) {
                float4 v4 = ld4(&hp[(size_t)(m0 + r) * 516 + kc + i4]);
                T[i4 + 0][r] = v4.x; T[i4 + 1][r] = v4.y;
                T[i4 + 2][r] = v4.z; T[i4 + 3][r] = v4.w;
            }
        }
        __syncthreads();
        for (int k = 0; k < csz; ++k) {
            float2 a2 = ld2(&T[k][r0]);
            float4 w4 = ld4(&W1p[(size_t)(kc + k) * CP + o0]);
            const float* ap = (const float*)&a2;
            const float* wp = (const float*)&w4;
#pragma unroll
            for (int ri = 0; ri < 2; ++ri)
#pragma unroll
                for (int oi = 0; oi < 4; ++oi) acc[ri][oi] += ap[ri] * wp[oi];
            if (t < 64) accX += T[k][rX] * W1p[(size_t)(kc + k) * CP + oX];
        }
    }
    __syncthreads();
    // hidden^T (relu+bias) back into T; rows 129..131 zero
#pragma unroll
    for (int oi = 0; oi < 4; ++oi) {
        int o = o0 + oi;
        float bb = b1[o];
        st2(&T[o][r0], make_float2(fmaxf(acc[0][oi] + bb, 0.f), fmaxf(acc[1][oi] + bb, 0.f)));
    }
    if (t < 64) T[oX][rX] = (oX == 128) ? fmaxf(accX + b1[128], 0.f) : 0.f;
    __syncthreads();
    // ---- GEMM2: out = hidden @ W2 + b2 + skip ----
    float acc2[2][4] = {{0.f}};
    float accX2 = 0.f;
    for (int k = 0; k < C_; ++k) {
        float2 a2 = ld2(&T[k][r0]);
        float4 w4 = ld4(&W2p[(size_t)k * CP + o0]);
        const float* ap = (const float*)&a2;
        const float* wp = (const float*)&w4;
#pragma unroll
        for (int ri = 0; ri < 2; ++ri)
#pragma unroll
            for (int oi = 0; oi < 4; ++oi) acc2[ri][oi] += ap[ri] * wp[oi];
        if (t < 64) accX2 += T[k][rX] * W2p[(size_t)k * CP + oX];
    }
#pragma unroll
    for (int ri = 0; ri < 2; ++ri) {
        int m = m0 + r0 + ri;
        int b = nb[m], n = nn[m];
        const float* xr = &x[(b * N_ + n) * 65];
        const float* hr = &h[(b * N_ + n) * D_];
        float o4[4];
#pragma unroll
        for (int oi = 0; oi < 4; ++oi) {
            int o = o0 + oi;
            float sk = (o < 65) ? xr[o] : hr[o - 65];
            o4[oi] = acc2[ri][oi] + b2[o] + sk;
        }
        st4(&cpost[(size_t)m * CP + o0], make_float4(o4[0], o4[1], o4[2], o4[3]));
    }
    if (t < 64) {
        int m = m0 + rX;
        if (oX == 128) {
            int b = nb[m], n = nn[m];
            cpost[(size_t)m * CP + 128] = accX2 + b2[128] + h[(b * N_ + n) * D_ + 63];
        } else {
            cpost[(size_t)m * CP + oX] = 0.f;
        }
    }
}

// ---------------- K5: hypernetwork partials; 32-row tiles ----------------
__global__ __launch_bounds__(256) void k_hyper(
    const float* __restrict__ src,   // [M][CP]
    const float* __restrict__ Wa, const float* __restrict__ ba,
    const float* __restrict__ Wb, const float* __restrict__ bb,
    const float* __restrict__ qv,
    float* __restrict__ parts, int two_calls, int dpb) {
    __shared__ float selT[C_][36];
    __shared__ float qvT[QV_][36];
    const int t = threadIdx.x;
    const int m0 = blockIdx.x * 32;
    const int spc = 32 / dpb;
    int call, ds;
    if (two_calls) { call = blockIdx.y / spc; ds = blockIdx.y % spc; }
    else { call = 0; ds = blockIdx.y; }
    const int d0 = ds * dpb;
    const float* W = call ? Wb : Wa;
    const float* bias = call ? bb : ba;
    for (int idx = t; idx < 32 * 33; idx += 256) {
        int r = idx / 33, i4 = (idx - r * 33) * 4;
        float4 v4 = ld4(&src[(size_t)(m0 + r) * CP + i4]);
        const float* vv = (const float*)&v4;
#pragma unroll
        for (int w = 0; w < 4; ++w) { int i = i4 + w; if (i < C_) selT[i][r] = vv[w]; }
    }
    for (int idx = t; idx < 32 * 8; idx += 256) {
        int r = idx >> 3, d4 = (idx & 7) * 4;
        float4 v4 = ld4(&qv[(size_t)(m0 + r) * QV_ + d4]);
        const float* vv = (const float*)&v4;
#pragma unroll
        for (int w = 0; w < 4; ++w) qvT[d4 + w][r] = vv[w];
    }
    __syncthreads();
    const int r0 = (t >> 4) * 2, o0 = (t & 15) * 4;   // 16 rowgroups x 16 colgroups
    float acc[2][4] = {{0.f}};
    for (int dg = 0; dg < dpb; ++dg) {
        int d = d0 + dg;
        float4 b4 = ld4(&bias[(size_t)d * D_ + o0]);
        const float* Wrow = &W[((size_t)d * C_) * D_ + o0];
        float part[2][4] = {{0.f}};
        for (int i = 0; i < C_; ++i) {
            float2 s2 = ld2(&selT[i][r0]);
            float4 w4 = ld4(Wrow + (size_t)i * D_);
            const float* sp = (const float*)&s2;
            const float* wp = (const float*)&w4;
#pragma unroll
            for (int ri = 0; ri < 2; ++ri)
#pragma unroll
                for (int oi = 0; oi < 4; ++oi) part[ri][oi] += sp[ri] * wp[oi];
        }
        float2 q2 = ld2(&qvT[d][r0]);
        const float* qp = (const float*)&q2;
        const float* bp = (const float*)&b4;
#pragma unroll
        for (int ri = 0; ri < 2; ++ri)
#pragma unroll
            for (int oi = 0; oi < 4; ++oi) acc[ri][oi] += qp[ri] * (part[ri][oi] + bp[oi]);
    }
    const int sl = call * spc + ds;
#pragma unroll
    for (int ri = 0; ri < 2; ++ri)
        st4(&parts[((size_t)sl * M_ + m0 + r0 + ri) * D_ + o0],
            make_float4(acc[ri][0], acc[ri][1], acc[ri][2], acc[ri][3]));
}

// ---------------- K5b: build cin[M][CP] = [x_sel, sigmoid(r)*h_sel, 0pad] ----------------
__global__ void k_build_cin(const float* __restrict__ x, const float* __restrict__ h,
                            const int* __restrict__ nb, const int* __restrict__ nn,
                            const float* __restrict__ pru, float* __restrict__ cin) {
    int idx = blockIdx.x * 256 + threadIdx.x;
    if (idx >= M_ * CP) return;
    int m = idx / CP, i = idx - m * CP;
    int b = nb[m], n = nn[m];
    float val;
    if (i < 65) val = x[(b * N_ + n) * 65 + i];
    else if (i < C_) {
        int o = i - 65;
        size_t base = (size_t)m * D_ + o;
        const size_t S = (size_t)M_ * D_;
        float s = pru[base] + pru[S + base] + pru[2 * S + base] + pru[3 * S + base];
        float rv = 1.f / (1.f + __expf(-s));
        val = rv * h[(b * N_ + n) * D_ + o];
    } else val = 0.f;
    cin[idx] = val;
}

// ---------------- K5d: final gate ----------------
__global__ void k_final(const float* __restrict__ pru, const float* __restrict__ pc,
                        const float* __restrict__ cin, float* __restrict__ out) {
    int idx = blockIdx.x * 256 + threadIdx.x;
    if (idx >= M_ * D_) return;
    int m = idx >> 6, o = idx & 63;
    size_t base = (size_t)m * D_ + o;
    const size_t S = (size_t)M_ * D_;
    float su = pru[4 * S + base] + pru[5 * S + base] + pru[6 * S + base] + pru[7 * S + base];
    float uv = 1.f / (1.f + __expf(-su));
    float sc = pc[base] + pc[S + base] + pc[2 * S + base] + pc[3 * S + base]
             + pc[4 * S + base] + pc[5 * S + base] + pc[6 * S + base] + pc[7 * S + base];
    float cand = tanhf(sc);
    float hn = cin[(size_t)m * CP + 65 + o];
    out[idx] = (1.f - uv) * hn + uv * cand;
}

extern "C" void kernel_launch(void* const* d_in, const int* in_sizes, int n_in,
                              void* d_out, int out_size, void* d_ws, size_t ws_size,
                              hipStream_t stream) {
    const float* x   = (const float*)d_in[0];
    const float* h   = (const float*)d_in[1];
    const float* qv  = (const float*)d_in[2];
    const int*   adj = (const int*)d_in[3];
    const int*   nb  = (const int*)d_in[4];
    const int*   nn  = (const int*)d_in[5];
    const float* Wq  = (const float*)d_in[6];
    const float* bq  = (const float*)d_in[7];
    const float* Wk  = (const float*)d_in[8];
    const float* bk  = (const float*)d_in[9];
    const float* Wv  = (const float*)d_in[10];
    const float* bv  = (const float*)d_in[11];
    const float* W1  = (const float*)d_in[12];
    const float* b1  = (const float*)d_in[13];
    const float* W2  = (const float*)d_in[14];
    const float* b2  = (const float*)d_in[15];
    const float* Wr  = (const float*)d_in[16];
    const float* br  = (const float*)d_in[17];
    const float* Wu  = (const float*)d_in[18];
    const float* bu  = (const float*)d_in[19];
    const float* Wc  = (const float*)d_in[20];
    const float* bc  = (const float*)d_in[21];
    float* ws = (float*)d_ws;
    float* out = (float*)d_out;

    float* Wvp   = ws + o_Wvp;
    float* qo    = ws + o_q;
    float* ko    = ws + o_k;
    float* vo    = ws + o_v;
    float* hp    = ws + o_hp;
    float* cpost = ws + o_cpost;
    float* W1p   = ws + o_W1p;
    float* W2p   = ws + o_W2p;
    float* lsum  = ws + o_lsum;
    float* pru   = ws + o_pru;
    float* cin   = ws + o_cin;
    float* pc    = ws + o_pc;

    const int prep_tot = H_ * C_ * CP + 516 * CP + C_ * CP;
    k_prep<<<(prep_tot + 255) / 256, 256, 0, stream>>>(Wv, Wvp, W1, W1p, W2, W2p);
    k_zero<<<(M_ * 516 + 255) / 256, 256, 0, stream>>>(hp, lsum);
    k_qkv<<<dim3(NG / 32, H_), 256, 0, stream>>>(x, h, Wq, bq, Wk, bk, Wvp, bv, qo, ko, vo);
    k_attn<<<dim3(M_ / 32, H_, 4), 256, 0, stream>>>(qo, ko, vo, adj, nb, nn, hp, lsum);
    k_norm<<<(M_ * 516 + 255) / 256, 256, 0, stream>>>(hp, lsum);
    k_mlp<<<M_ / 16, 256, 0, stream>>>(hp, W1p, b1, W2p, b2, x, h, nb, nn, cpost);
    k_hyper<<<dim3(M_ / 32, 8), 256, 0, stream>>>(cpost, Wr, br, Wu, bu, qv, pru, 1, 8);
    k_build_cin<<<(M_ * CP) / 256, 256, 0, stream>>>(x, h, nb, nn, pru, cin);
    k_hyper<<<dim3(M_ / 32, 8), 256, 0, stream>>>(cin, Wc, bc, Wc, bc, qv, pc, 0, 4);
    k_final<<<(M_ * D_) / 256, 256, 0, stream>>>(pru, pc, cin, out);
}

// Round 5
// 573.484 us; speedup vs baseline: 1.2246x; 1.2246x over previous
//
#include <hip/hip_runtime.h>

#define DEVINL __device__ __forceinline__

typedef unsigned short ushort_t;
typedef __attribute__((ext_vector_type(8))) short short8;
typedef __attribute__((ext_vector_type(8))) unsigned short ushort8;
typedef __attribute__((ext_vector_type(4))) unsigned short ushort4v;
typedef __attribute__((ext_vector_type(4))) float f32x4;

constexpr int B_ = 8, N_ = 1024, D_ = 64, H_ = 4, QV_ = 32;
constexpr int C_ = 129, K_ = 16, M_ = 4096;
constexpr int CP = 132;              // padded C (multiple of 4)
constexpr int NG = B_ * N_;          // 8192 nodes total
constexpr int VBS = 136;             // vb bf16 row stride
constexpr int VTN = 144;             // vT padded n-dim (9 MFMA n-tiles)

// ---- workspace layout (float offsets) ----
constexpr size_t o_Wvp   = 0;                                   // H*C*CP
constexpr size_t o_q     = o_Wvp + (size_t)H_ * C_ * CP;        // H*NG*K
constexpr size_t o_k     = o_q   + (size_t)H_ * NG * K_;        // H*NG*K
constexpr size_t o_vb    = o_k   + (size_t)H_ * NG * K_;        // H*NG*136 ushort
constexpr size_t o_vT    = o_vb  + (size_t)H_ * NG * VBS / 2;   // H*144*NG ushort
constexpr size_t o_hp    = o_vT  + (size_t)H_ * VTN * NG / 2;   // M*516
constexpr size_t o_cpost = o_hp  + (size_t)M_ * 516;            // M*CP
constexpr size_t o_W1p   = o_cpost + (size_t)M_ * CP;           // 516*CP
constexpr size_t o_W2p   = o_W1p + (size_t)516 * CP;            // 129*CP
// aliases (lifetimes disjoint)
constexpr size_t o_pru = o_vb;     // 8*M*64 (after attn, vb+vT dead)
constexpr size_t o_cin = o_q;      // M*CP   (after attn, q+k dead)
constexpr size_t o_pc  = o_hp;     // 8*M*64 (after mlp, hp dead)

DEVINL float4 ld4(const float* p) { return *reinterpret_cast<const float4*>(p); }
DEVINL float2 ld2(const float* p) { return *reinterpret_cast<const float2*>(p); }
DEVINL void st4(float* p, float4 v) { *reinterpret_cast<float4*>(p) = v; }
DEVINL void st2(float* p, float2 v) { *reinterpret_cast<float2*>(p) = v; }
DEVINL ushort_t f2bf(float f) {           // RNE fp32->bf16
    unsigned int u = __float_as_uint(f);
    u += 0x7FFFu + ((u >> 16) & 1u);
    return (ushort_t)(u >> 16);
}

// ---------------- K0: pad Wv,W1,W2 into [*][CP] layouts ----------------
__global__ void k_prep(const float* __restrict__ Wv, float* __restrict__ Wvp,
                       const float* __restrict__ W1, float* __restrict__ W1p,
                       const float* __restrict__ W2, float* __restrict__ W2p) {
    int idx = blockIdx.x * 256 + threadIdx.x;
    const int totV = H_ * C_ * CP;
    const int tot1 = 516 * CP;
    const int tot2 = C_ * CP;
    if (idx < totV) {
        int hh = idx / (C_ * CP); int rem = idx - hh * C_ * CP;
        int cc = rem / CP;        int o  = rem - cc * CP;
        Wvp[idx] = (o < C_) ? Wv[(hh * C_ + cc) * C_ + o] : 0.f;
    } else if (idx < totV + tot1) {
        int r = (idx - totV) / CP, o = (idx - totV) - ((idx - totV) / CP) * CP;
        W1p[r * CP + o] = (o < C_) ? W1[r * C_ + o] : 0.f;
    } else if (idx < totV + tot1 + tot2) {
        int j = idx - totV - tot1;
        int r = j / CP, o = j - r * CP;
        W2p[r * CP + o] = (o < C_) ? W2[r * C_ + o] : 0.f;
    }
}

// ---------------- K1: combined -> q,k fp32; v -> bf16 [h][g][136] ----------------
__global__ __launch_bounds__(256) void k_qkv(
    const float* __restrict__ x, const float* __restrict__ h,
    const float* __restrict__ Wq, const float* __restrict__ bq,
    const float* __restrict__ Wk, const float* __restrict__ bk,
    const float* __restrict__ Wvp, const float* __restrict__ bv,
    float* __restrict__ qo, float* __restrict__ ko, ushort_t* __restrict__ vb) {
    __shared__ float Cs[32][CP];
    const int t = threadIdx.x;
    const int g0 = blockIdx.x * 32;
    const int hh = blockIdx.y;
    for (int idx = t; idx < 32 * C_; idx += 256) {
        int r = idx / C_, cc = idx - r * C_;
        int g = g0 + r; int b = g >> 10, n = g & (N_ - 1);
        Cs[r][cc] = (cc < 65) ? x[(b * N_ + n) * 65 + cc]
                              : h[(b * N_ + n) * D_ + (cc - 65)];
    }
    __syncthreads();
    {
        const int r = (t & 127) >> 2, kb = (t & 3) * 4;
        const float* W = (t < 128) ? Wq : Wk;
        const float* bb = (t < 128) ? bq : bk;
        float a[4];
#pragma unroll
        for (int j = 0; j < 4; ++j) a[j] = bb[hh * K_ + kb + j];
        for (int cc = 0; cc < C_; ++cc) {
            float s = Cs[r][cc];
            float4 w = ld4(&W[(size_t)(hh * C_ + cc) * K_ + kb]);
            a[0] += s * w.x; a[1] += s * w.y; a[2] += s * w.z; a[3] += s * w.w;
        }
        float* dst = (t < 128) ? qo : ko;
        st4(&dst[(size_t)(hh * NG + g0 + r) * K_ + kb], make_float4(a[0], a[1], a[2], a[3]));
    }
    // v cols 0..127 -> bf16
    for (int jj = 0; jj < 4; ++jj) {
        int idx = t + 256 * jj;
        int r = idx >> 5, o4 = (idx & 31) * 4;
        float a0 = bv[hh * C_ + o4 + 0], a1 = bv[hh * C_ + o4 + 1],
              a2 = bv[hh * C_ + o4 + 2], a3 = bv[hh * C_ + o4 + 3];
        for (int cc = 0; cc < C_; ++cc) {
            float s = Cs[r][cc];
            float4 w = ld4(&Wvp[(size_t)(hh * C_ + cc) * CP + o4]);
            a0 += s * w.x; a1 += s * w.y; a2 += s * w.z; a3 += s * w.w;
        }
        ushort4v vv; vv.x = f2bf(a0); vv.y = f2bf(a1); vv.z = f2bf(a2); vv.w = f2bf(a3);
        *reinterpret_cast<ushort4v*>(&vb[(size_t)(hh * NG + g0 + r) * VBS + o4]) = vv;
    }
    // v col 128 + zero cols 129..135
    if (t < 32) {
        int r = t;
        float a = bv[hh * C_ + 128];
        for (int cc = 0; cc < C_; ++cc) a += Cs[r][cc] * Wvp[(size_t)(hh * C_ + cc) * CP + 128];
        ushort_t* vp = &vb[(size_t)(hh * NG + g0 + r) * VBS];
        ushort4v v1; v1.x = f2bf(a); v1.y = 0; v1.z = 0; v1.w = 0;
        *reinterpret_cast<ushort4v*>(vp + 128) = v1;
        ushort4v z; z.x = 0; z.y = 0; z.z = 0; z.w = 0;
        *reinterpret_cast<ushort4v*>(vp + 132) = z;
    }
}

// ---------------- K2: transpose vb [h][g][136] -> vT [h][n=0..143][g] (bf16) ----------------
__global__ __launch_bounds__(256) void k_vtrans(const ushort_t* __restrict__ vb,
                                                ushort_t* __restrict__ vTg) {
    __shared__ ushort_t T[136 * 72];
    const int t = threadIdx.x;
    const int g0 = blockIdx.x * 64;
    const int hh = blockIdx.y;
    for (int idx = t; idx < 64 * 17; idx += 256) {
        int row = idx / 17, c8 = (idx - row * 17) * 8;
        ushort8 v = *reinterpret_cast<const ushort8*>(&vb[(size_t)(hh * NG + g0 + row) * VBS + c8]);
#pragma unroll
        for (int i = 0; i < 8; ++i) T[(c8 + i) * 72 + row] = v[i];
    }
    __syncthreads();
    for (int idx = t; idx < VTN * 8; idx += 256) {
        int n = idx >> 3, gl = idx & 7;
        ushort8 o;
        if (n < 136) o = *reinterpret_cast<const ushort8*>(&T[n * 72 + gl * 8]);
        else { o = ushort8{0,0,0,0,0,0,0,0}; }
        *reinterpret_cast<ushort8*>(&vTg[(size_t)(hh * VTN + n) * NG + g0 + gl * 8]) = o;
    }
}

// ---------------- K3: attention — scalar QK/softmax + MFMA bf16 PV ----------------
// grid (M/16, H), block 256 (4 waves). 16-row Q-tiles, 64-col K/V tiles.
__global__ __launch_bounds__(256) void k_attn(
    const float* __restrict__ qg, const float* __restrict__ kg,
    const ushort_t* __restrict__ vTg,
    const int* __restrict__ adj, const int* __restrict__ nodes_b, const int* __restrict__ nodes_n,
    float* __restrict__ hp) {
    __shared__ alignas(16) float Ks[64 * 20];          // K tile fp32 [c][16] stride 20
    __shared__ alignas(16) ushort_t Vt[VTN * 72];      // V^T tile bf16 [n][64k] stride 72
    __shared__ alignas(16) ushort_t Pb[16 * 72];       // P tile bf16 [m][64k] stride 72
    __shared__ float Lrow[16];
    __shared__ int Nrow[16];
    const int t = threadIdx.x;
    const int m0 = blockIdx.x * 16;
    const int hh = blockIdx.y;
    const int b = nodes_b[m0];
    if (t < 16) Nrow[t] = nodes_n[m0 + t];
    __syncthreads();
    const int r = t >> 4, cl = t & 15;                 // score mapping: 16 rows x 16 lanes
    float qreg[16];
    {
        const float* qp = &qg[(size_t)(hh * NG + b * N_ + Nrow[r]) * K_];
#pragma unroll
        for (int w4 = 0; w4 < 16; w4 += 4) {
            float4 qq = ld4(qp + w4);
            qreg[w4] = qq.x; qreg[w4 + 1] = qq.y; qreg[w4 + 2] = qq.z; qreg[w4 + 3] = qq.w;
        }
    }
    const int* adjrow = &adj[(size_t)Nrow[r] * N_];
    const int lane = t & 63, w = t >> 6;
    const int am = lane & 15, aq = lane >> 4;
    f32x4 accv[5];
#pragma unroll
    for (int s = 0; s < 5; ++s) accv[s] = f32x4{0.f, 0.f, 0.f, 0.f};
    float lsum = 0.f;

    for (int ct = 0; ct < 16; ++ct) {
        const int c0 = ct * 64;
        __syncthreads();
        { // stage K tile fp32
            int row = t >> 2, k4 = (t & 3) * 4;
            st4(&Ks[row * 20 + k4], ld4(&kg[(size_t)(hh * NG + b * N_ + c0 + row) * K_ + k4]));
        }
        for (int idx = t; idx < VTN * 8; idx += 256) { // stage V^T tile bf16 (all 64 k-cols!)
            int n = idx >> 3, l8 = idx & 7;
            *reinterpret_cast<ushort8*>(&Vt[n * 72 + l8 * 8]) =
                *reinterpret_cast<const ushort8*>(&vTg[(size_t)(hh * VTN + n) * NG + b * N_ + c0 + l8 * 8]);
        }
        __syncthreads();
        // scores: each thread 4 cols (cl + 16j)
#pragma unroll
        for (int j = 0; j < 4; ++j) {
            int c = cl + 16 * j;
            const float* kc = &Ks[c * 20];
            float4 k0 = ld4(kc), k1 = ld4(kc + 4), k2 = ld4(kc + 8), k3 = ld4(kc + 12);
            float dot = qreg[0]*k0.x + qreg[1]*k0.y + qreg[2]*k0.z + qreg[3]*k0.w
                      + qreg[4]*k1.x + qreg[5]*k1.y + qreg[6]*k1.z + qreg[7]*k1.w
                      + qreg[8]*k2.x + qreg[9]*k2.y + qreg[10]*k2.z + qreg[11]*k2.w
                      + qreg[12]*k3.x + qreg[13]*k3.y + qreg[14]*k3.z + qreg[15]*k3.w;
            float s = dot * 0.25f;
            s = (s >= 0.f) ? s : 0.2f * s;
            float p = adjrow[c0 + c] ? __expf(s) : 0.f;
            lsum += p;
            Pb[r * 72 + c] = f2bf(p);
        }
        __syncthreads();
        // PV: 9 n-tiles x 2 k-halves = 18 MFMA units over 4 waves
#pragma unroll
        for (int s = 0; s < 5; ++s) {
            int u = 4 * s + w;
            if (u < 18) {
                int nt = u >> 1, kh = u & 1;
                short8 af = *reinterpret_cast<const short8*>(&Pb[am * 72 + kh * 32 + aq * 8]);
                short8 bfr = *reinterpret_cast<const short8*>(&Vt[(nt * 16 + am) * 72 + kh * 32 + aq * 8]);
                accv[s] = __builtin_amdgcn_mfma_f32_16x16x32_bf16(af, bfr, accv[s], 0, 0, 0);
            }
        }
    }
    // row sums -> Linv
    lsum += __shfl_xor(lsum, 1);
    lsum += __shfl_xor(lsum, 2);
    lsum += __shfl_xor(lsum, 4);
    lsum += __shfl_xor(lsum, 8);
    if (cl == 0) Lrow[r] = lsum;
    __syncthreads();
    float* Ored = reinterpret_cast<float*>(Vt);   // overlay: Vt dead now
    if (w & 1) {                                   // kh=1 owners stash partials
#pragma unroll
        for (int s = 0; s < 5; ++s) {
            int u = 4 * s + w;
            if (u < 18) {
                int nt = u >> 1;
#pragma unroll
                for (int i = 0; i < 4; ++i)
                    Ored[(aq * 4 + i) * 160 + nt * 16 + am] = accv[s][i];
            }
        }
    }
    if (t < 16) Lrow[t] = (Lrow[t] > 0.f) ? 1.f / Lrow[t] : 0.f;
    __syncthreads();
    if (!(w & 1)) {                                // kh=0 owners combine + store
#pragma unroll
        for (int s = 0; s < 5; ++s) {
            int u = 4 * s + w;
            if (u < 18) {
                int nt = u >> 1;
                int col = nt * 16 + am;
                if (col < C_) {
#pragma unroll
                    for (int i = 0; i < 4; ++i) {
                        int row = aq * 4 + i;
                        float val = (accv[s][i] + Ored[row * 160 + col]) * Lrow[row];
                        hp[(size_t)(m0 + row) * 516 + hh * C_ + col] = val;
                    }
                }
            }
        }
    }
}

// ---------------- K4: node MLP + skip -> cpost[M][CP]; 16-row tiles ----------------
__global__ __launch_bounds__(256) void k_mlp(
    const float* __restrict__ hp,
    const float* __restrict__ W1p, const float* __restrict__ b1,
    const float* __restrict__ W2p, const float* __restrict__ b2,
    const float* __restrict__ x, const float* __restrict__ h,
    const int* __restrict__ nb, const int* __restrict__ nn,
    float* __restrict__ cpost) {
    __shared__ float T[CP][20];
    const int t = threadIdx.x;
    const int m0 = blockIdx.x * 16;
    const int r0 = (t >> 5) * 2;
    const int o0 = (t & 31) * 4;
    const int rX = (t < 64) ? (t >> 2) : 0;
    const int oX = 128 + (t & 3);
    float acc[2][4] = {{0.f}};
    float accX = 0.f;
    for (int chunk = 0; chunk < 4; ++chunk) {
        const int kc = chunk * 132;
        const int csz = (chunk < 3) ? 132 : 120;
        __syncthreads();
        for (int idx = t; idx < 16 * 33; idx += 256) {
            int rr = idx / 33, i4 = (idx - rr * 33) * 4;
            if (i4 + 3 < csz) {
                float4 v4 = ld4(&hp[(size_t)(m0 + rr) * 516 + kc + i4]);
                T[i4 + 0][rr] = v4.x; T[i4 + 1][rr] = v4.y;
                T[i4 + 2][rr] = v4.z; T[i4 + 3][rr] = v4.w;
            }
        }
        __syncthreads();
        for (int k = 0; k < csz; ++k) {
            float2 a2 = ld2(&T[k][r0]);
            float4 w4 = ld4(&W1p[(size_t)(kc + k) * CP + o0]);
            const float* ap = (const float*)&a2;
            const float* wp = (const float*)&w4;
#pragma unroll
            for (int ri = 0; ri < 2; ++ri)
#pragma unroll
                for (int oi = 0; oi < 4; ++oi) acc[ri][oi] += ap[ri] * wp[oi];
            if (t < 64) accX += T[k][rX] * W1p[(size_t)(kc + k) * CP + oX];
        }
    }
    __syncthreads();
#pragma unroll
    for (int oi = 0; oi < 4; ++oi) {
        int o = o0 + oi;
        float bb = b1[o];
        st2(&T[o][r0], make_float2(fmaxf(acc[0][oi] + bb, 0.f), fmaxf(acc[1][oi] + bb, 0.f)));
    }
    if (t < 64) T[oX][rX] = (oX == 128) ? fmaxf(accX + b1[128], 0.f) : 0.f;
    __syncthreads();
    float acc2[2][4] = {{0.f}};
    float accX2 = 0.f;
    for (int k = 0; k < C_; ++k) {
        float2 a2 = ld2(&T[k][r0]);
        float4 w4 = ld4(&W2p[(size_t)k * CP + o0]);
        const float* ap = (const float*)&a2;
        const float* wp = (const float*)&w4;
#pragma unroll
        for (int ri = 0; ri < 2; ++ri)
#pragma unroll
            for (int oi = 0; oi < 4; ++oi) acc2[ri][oi] += ap[ri] * wp[oi];
        if (t < 64) accX2 += T[k][rX] * W2p[(size_t)k * CP + oX];
    }
#pragma unroll
    for (int ri = 0; ri < 2; ++ri) {
        int m = m0 + r0 + ri;
        int b = nb[m], n = nn[m];
        const float* xr = &x[(b * N_ + n) * 65];
        const float* hr = &h[(b * N_ + n) * D_];
        float o4[4];
#pragma unroll
        for (int oi = 0; oi < 4; ++oi) {
            int o = o0 + oi;
            float sk = (o < 65) ? xr[o] : hr[o - 65];
            o4[oi] = acc2[ri][oi] + b2[o] + sk;
        }
        st4(&cpost[(size_t)m * CP + o0], make_float4(o4[0], o4[1], o4[2], o4[3]));
    }
    if (t < 64) {
        int m = m0 + rX;
        if (oX == 128) {
            int b = nb[m], n = nn[m];
            cpost[(size_t)m * CP + 128] = accX2 + b2[128] + h[(b * N_ + n) * D_ + 63];
        } else {
            cpost[(size_t)m * CP + oX] = 0.f;
        }
    }
}

// ---------------- K5: hypernetwork partials; 32-row tiles ----------------
__global__ __launch_bounds__(256) void k_hyper(
    const float* __restrict__ src,   // [M][CP]
    const float* __restrict__ Wa, const float* __restrict__ ba,
    const float* __restrict__ Wb, const float* __restrict__ bb,
    const float* __restrict__ qv,
    float* __restrict__ parts, int two_calls, int dpb) {
    __shared__ float selT[C_][36];
    __shared__ float qvT[QV_][36];
    const int t = threadIdx.x;
    const int m0 = blockIdx.x * 32;
    const int spc = 32 / dpb;
    int call, ds;
    if (two_calls) { call = blockIdx.y / spc; ds = blockIdx.y % spc; }
    else { call = 0; ds = blockIdx.y; }
    const int d0 = ds * dpb;
    const float* W = call ? Wb : Wa;
    const float* bias = call ? bb : ba;
    for (int idx = t; idx < 32 * 33; idx += 256) {
        int rr = idx / 33, i4 = (idx - rr * 33) * 4;
        float4 v4 = ld4(&src[(size_t)(m0 + rr) * CP + i4]);
        const float* vv = (const float*)&v4;
#pragma unroll
        for (int w = 0; w < 4; ++w) { int i = i4 + w; if (i < C_) selT[i][rr] = vv[w]; }
    }
    for (int idx = t; idx < 32 * 8; idx += 256) {
        int rr = idx >> 3, d4 = (idx & 7) * 4;
        float4 v4 = ld4(&qv[(size_t)(m0 + rr) * QV_ + d4]);
        const float* vv = (const float*)&v4;
#pragma unroll
        for (int w = 0; w < 4; ++w) qvT[d4 + w][rr] = vv[w];
    }
    __syncthreads();
    const int r0 = (t >> 4) * 2, o0 = (t & 15) * 4;
    float acc[2][4] = {{0.f}};
    for (int dg = 0; dg < dpb; ++dg) {
        int d = d0 + dg;
        float4 b4 = ld4(&bias[(size_t)d * D_ + o0]);
        const float* Wrow = &W[((size_t)d * C_) * D_ + o0];
        float part[2][4] = {{0.f}};
        for (int i = 0; i < C_; ++i) {
            float2 s2 = ld2(&selT[i][r0]);
            float4 w4 = ld4(Wrow + (size_t)i * D_);
            const float* sp = (const float*)&s2;
            const float* wp = (const float*)&w4;
#pragma unroll
            for (int ri = 0; ri < 2; ++ri)
#pragma unroll
                for (int oi = 0; oi < 4; ++oi) part[ri][oi] += sp[ri] * wp[oi];
        }
        float2 q2 = ld2(&qvT[d][r0]);
        const float* qp = (const float*)&q2;
        const float* bp = (const float*)&b4;
#pragma unroll
        for (int ri = 0; ri < 2; ++ri)
#pragma unroll
            for (int oi = 0; oi < 4; ++oi) acc[ri][oi] += qp[ri] * (part[ri][oi] + bp[oi]);
    }
    const int sl = call * spc + ds;
#pragma unroll
    for (int ri = 0; ri < 2; ++ri)
        st4(&parts[((size_t)sl * M_ + m0 + r0 + ri) * D_ + o0],
            make_float4(acc[ri][0], acc[ri][1], acc[ri][2], acc[ri][3]));
}

// ---------------- K5b: build cin[M][CP] = [x_sel, sigmoid(r)*h_sel, 0pad] ----------------
__global__ void k_build_cin(const float* __restrict__ x, const float* __restrict__ h,
                            const int* __restrict__ nb, const int* __restrict__ nn,
                            const float* __restrict__ pru, float* __restrict__ cin) {
    int idx = blockIdx.x * 256 + threadIdx.x;
    if (idx >= M_ * CP) return;
    int m = idx / CP, i = idx - m * CP;
    int b = nb[m], n = nn[m];
    float val;
    if (i < 65) val = x[(b * N_ + n) * 65 + i];
    else if (i < C_) {
        int o = i - 65;
        size_t base = (size_t)m * D_ + o;
        const size_t S = (size_t)M_ * D_;
        float s = pru[base] + pru[S + base] + pru[2 * S + base] + pru[3 * S + base];
        float rv = 1.f / (1.f + __expf(-s));
        val = rv * h[(b * N_ + n) * D_ + o];
    } else val = 0.f;
    cin[idx] = val;
}

// ---------------- K5d: final gate ----------------
__global__ void k_final(const float* __restrict__ pru, const float* __restrict__ pc,
                        const float* __restrict__ cin, float* __restrict__ out) {
    int idx = blockIdx.x * 256 + threadIdx.x;
    if (idx >= M_ * D_) return;
    int m = idx >> 6, o = idx & 63;
    size_t base = (size_t)m * D_ + o;
    const size_t S = (size_t)M_ * D_;
    float su = pru[4 * S + base] + pru[5 * S + base] + pru[6 * S + base] + pru[7 * S + base];
    float uv = 1.f / (1.f + __expf(-su));
    float sc = pc[base] + pc[S + base] + pc[2 * S + base] + pc[3 * S + base]
             + pc[4 * S + base] + pc[5 * S + base] + pc[6 * S + base] + pc[7 * S + base];
    float cand = tanhf(sc);
    float hn = cin[(size_t)m * CP + 65 + o];
    out[idx] = (1.f - uv) * hn + uv * cand;
}

extern "C" void kernel_launch(void* const* d_in, const int* in_sizes, int n_in,
                              void* d_out, int out_size, void* d_ws, size_t ws_size,
                              hipStream_t stream) {
    const float* x   = (const float*)d_in[0];
    const float* h   = (const float*)d_in[1];
    const float* qv  = (const float*)d_in[2];
    const int*   adj = (const int*)d_in[3];
    const int*   nb  = (const int*)d_in[4];
    const int*   nn  = (const int*)d_in[5];
    const float* Wq  = (const float*)d_in[6];
    const float* bq  = (const float*)d_in[7];
    const float* Wk  = (const float*)d_in[8];
    const float* bk  = (const float*)d_in[9];
    const float* Wv  = (const float*)d_in[10];
    const float* bv  = (const float*)d_in[11];
    const float* W1  = (const float*)d_in[12];
    const float* b1  = (const float*)d_in[13];
    const float* W2  = (const float*)d_in[14];
    const float* b2  = (const float*)d_in[15];
    const float* Wr  = (const float*)d_in[16];
    const float* br  = (const float*)d_in[17];
    const float* Wu  = (const float*)d_in[18];
    const float* bu  = (const float*)d_in[19];
    const float* Wc  = (const float*)d_in[20];
    const float* bc  = (const float*)d_in[21];
    float* ws = (float*)d_ws;
    float* out = (float*)d_out;

    float* Wvp   = ws + o_Wvp;
    float* qo    = ws + o_q;
    float* ko    = ws + o_k;
    ushort_t* vb  = (ushort_t*)(ws + o_vb);
    ushort_t* vTg = (ushort_t*)(ws + o_vT);
    float* hp    = ws + o_hp;
    float* cpost = ws + o_cpost;
    float* W1p   = ws + o_W1p;
    float* W2p   = ws + o_W2p;
    float* pru   = ws + o_pru;
    float* cin   = ws + o_cin;
    float* pc    = ws + o_pc;

    const int prep_tot = H_ * C_ * CP + 516 * CP + C_ * CP;
    k_prep<<<(prep_tot + 255) / 256, 256, 0, stream>>>(Wv, Wvp, W1, W1p, W2, W2p);
    k_qkv<<<dim3(NG / 32, H_), 256, 0, stream>>>(x, h, Wq, bq, Wk, bk, Wvp, bv, qo, ko, vb);
    k_vtrans<<<dim3(NG / 64, H_), 256, 0, stream>>>(vb, vTg);
    k_attn<<<dim3(M_ / 16, H_), 256, 0, stream>>>(qo, ko, vTg, adj, nb, nn, hp);
    k_mlp<<<M_ / 16, 256, 0, stream>>>(hp, W1p, b1, W2p, b2, x, h, nb, nn, cpost);
    k_hyper<<<dim3(M_ / 32, 8), 256, 0, stream>>>(cpost, Wr, br, Wu, bu, qv, pru, 1, 8);
    k_build_cin<<<(M_ * CP) / 256, 256, 0, stream>>>(x, h, nb, nn, pru, cin);
    k_hyper<<<dim3(M_ / 32, 8), 256, 0, stream>>>(cin, Wc, bc, Wc, bc, qv, pc, 0, 4);
    k_final<<<(M_ * D_) / 256, 256, 0, stream>>>(pru, pc, cin, out);
}

// Round 6
// 477.938 us; speedup vs baseline: 1.4694x; 1.1999x over previous
//
#include <hip/hip_runtime.h>

#define DEVINL __device__ __forceinline__

typedef unsigned short ushort_t;
typedef __attribute__((ext_vector_type(8))) short short8;
typedef __attribute__((ext_vector_type(8))) unsigned short ushort8;
typedef __attribute__((ext_vector_type(4))) unsigned short ushort4v;
typedef __attribute__((ext_vector_type(4))) float f32x4;

constexpr int B_ = 8, N_ = 1024, D_ = 64, H_ = 4, QV_ = 32;
constexpr int C_ = 129, K_ = 16, M_ = 4096;
constexpr int CP = 132;              // padded C (multiple of 4)
constexpr int NG = B_ * N_;          // 8192 nodes total
constexpr int VBS = 136;             // vb bf16 row stride
constexpr int VTN = 144;             // vT padded n-dim (9 MFMA n-tiles)
constexpr int KT = 4256;             // hyper GEMM K: 32*132 + 32 bias slots (133 tiles of 32)
constexpr int NKT = 133;

// ---- workspace layout (float offsets) ----
constexpr size_t o_Wvp   = 0;                                   // H*C*CP
constexpr size_t o_q     = o_Wvp + (size_t)H_ * C_ * CP;        // H*NG*K
constexpr size_t o_k     = o_q   + (size_t)H_ * NG * K_;        // H*NG*K
constexpr size_t o_vb    = o_k   + (size_t)H_ * NG * K_;        // H*NG*136 ushort
constexpr size_t o_vT    = o_vb  + (size_t)H_ * NG * VBS / 2;   // H*144*NG ushort
constexpr size_t o_hp    = o_vT  + (size_t)H_ * VTN * NG / 2;   // M*516
constexpr size_t o_cpost = o_hp  + (size_t)M_ * 516;            // M*CP
constexpr size_t o_W1p   = o_cpost + (size_t)M_ * CP;           // 516*CP
constexpr size_t o_W2p   = o_W1p + (size_t)516 * CP;            // 129*CP
constexpr size_t o_wtru  = o_W2p + (size_t)C_ * CP;             // 128*KT ushort
constexpr size_t o_wtc   = o_wtru + (size_t)128 * KT / 2;       // 64*KT ushort
constexpr size_t o_A     = o_wtc + (size_t)64 * KT / 2;         // M*KT ushort
constexpr size_t o_pru   = o_A + (size_t)M_ * KT / 2;           // 4*M*128 fp32
constexpr size_t o_pc2   = o_pru + (size_t)4 * M_ * 128;        // 4*M*64 fp32
// aliases (lifetimes disjoint)
constexpr size_t o_cin = o_q;      // M*CP (after attn, q+k dead)

DEVINL float4 ld4(const float* p) { return *reinterpret_cast<const float4*>(p); }
DEVINL float2 ld2(const float* p) { return *reinterpret_cast<const float2*>(p); }
DEVINL void st4(float* p, float4 v) { *reinterpret_cast<float4*>(p) = v; }
DEVINL void st2(float* p, float2 v) { *reinterpret_cast<float2*>(p) = v; }
DEVINL ushort_t f2bf(float f) {           // RNE fp32->bf16
    unsigned int u = __float_as_uint(f);
    u += 0x7FFFu + ((u >> 16) & 1u);
    return (ushort_t)(u >> 16);
}

// ---------------- K0: pad Wv,W1,W2 into [*][CP] layouts ----------------
__global__ void k_prep(const float* __restrict__ Wv, float* __restrict__ Wvp,
                       const float* __restrict__ W1, float* __restrict__ W1p,
                       const float* __restrict__ W2, float* __restrict__ W2p) {
    int idx = blockIdx.x * 256 + threadIdx.x;
    const int totV = H_ * C_ * CP;
    const int tot1 = 516 * CP;
    const int tot2 = C_ * CP;
    if (idx < totV) {
        int hh = idx / (C_ * CP); int rem = idx - hh * C_ * CP;
        int cc = rem / CP;        int o  = rem - cc * CP;
        Wvp[idx] = (o < C_) ? Wv[(hh * C_ + cc) * C_ + o] : 0.f;
    } else if (idx < totV + tot1) {
        int r = (idx - totV) / CP, o = (idx - totV) - ((idx - totV) / CP) * CP;
        W1p[r * CP + o] = (o < C_) ? W1[r * C_ + o] : 0.f;
    } else if (idx < totV + tot1 + tot2) {
        int j = idx - totV - tot1;
        int r = j / CP, o = j - r * CP;
        W2p[r * CP + o] = (o < C_) ? W2[r * C_ + o] : 0.f;
    }
}

// ---------------- K0b: build WT_ru[128][KT], WT_c[64][KT] bf16 ----------------
// rows 0..63: Wr, 64..127: Wu, 128..191: Wc. k = d*132+i (i<129 real), k>=4224: bias d.
__global__ void k_wt(const float* __restrict__ Wr, const float* __restrict__ br,
                     const float* __restrict__ Wu, const float* __restrict__ bu,
                     const float* __restrict__ Wc, const float* __restrict__ bc,
                     ushort_t* __restrict__ wtru, ushort_t* __restrict__ wtc) {
    int idx = blockIdx.x * 256 + threadIdx.x;
    const int tot = 192 * KT;
    if (idx >= tot) return;
    int row = idx / KT, k = idx - row * KT;
    float v;
    if (k >= 4224) {
        int d = k - 4224;
        if (row < 64) v = br[d * 64 + row];
        else if (row < 128) v = bu[d * 64 + row - 64];
        else v = bc[d * 64 + row - 128];
    } else {
        int d = k / 132, i = k - d * 132;
        if (i >= 129) v = 0.f;
        else if (row < 64) v = Wr[(size_t)(d * 129 + i) * 64 + row];
        else if (row < 128) v = Wu[(size_t)(d * 129 + i) * 64 + row - 64];
        else v = Wc[(size_t)(d * 129 + i) * 64 + row - 128];
    }
    if (row < 128) wtru[(size_t)row * KT + k] = f2bf(v);
    else wtc[(size_t)(row - 128) * KT + k] = f2bf(v);
}

// ---------------- K1: combined -> q,k fp32; v -> bf16 [h][g][136] ----------------
__global__ __launch_bounds__(256) void k_qkv(
    const float* __restrict__ x, const float* __restrict__ h,
    const float* __restrict__ Wq, const float* __restrict__ bq,
    const float* __restrict__ Wk, const float* __restrict__ bk,
    const float* __restrict__ Wvp, const float* __restrict__ bv,
    float* __restrict__ qo, float* __restrict__ ko, ushort_t* __restrict__ vb) {
    __shared__ float Cs[32][CP];
    const int t = threadIdx.x;
    const int g0 = blockIdx.x * 32;
    const int hh = blockIdx.y;
    for (int idx = t; idx < 32 * C_; idx += 256) {
        int r = idx / C_, cc = idx - r * C_;
        int g = g0 + r; int b = g >> 10, n = g & (N_ - 1);
        Cs[r][cc] = (cc < 65) ? x[(b * N_ + n) * 65 + cc]
                              : h[(b * N_ + n) * D_ + (cc - 65)];
    }
    __syncthreads();
    {
        const int r = (t & 127) >> 2, kb = (t & 3) * 4;
        const float* W = (t < 128) ? Wq : Wk;
        const float* bb = (t < 128) ? bq : bk;
        float a[4];
#pragma unroll
        for (int j = 0; j < 4; ++j) a[j] = bb[hh * K_ + kb + j];
        for (int cc = 0; cc < C_; ++cc) {
            float s = Cs[r][cc];
            float4 w = ld4(&W[(size_t)(hh * C_ + cc) * K_ + kb]);
            a[0] += s * w.x; a[1] += s * w.y; a[2] += s * w.z; a[3] += s * w.w;
        }
        float* dst = (t < 128) ? qo : ko;
        st4(&dst[(size_t)(hh * NG + g0 + r) * K_ + kb], make_float4(a[0], a[1], a[2], a[3]));
    }
    for (int jj = 0; jj < 4; ++jj) {
        int idx = t + 256 * jj;
        int r = idx >> 5, o4 = (idx & 31) * 4;
        float a0 = bv[hh * C_ + o4 + 0], a1 = bv[hh * C_ + o4 + 1],
              a2 = bv[hh * C_ + o4 + 2], a3 = bv[hh * C_ + o4 + 3];
        for (int cc = 0; cc < C_; ++cc) {
            float s = Cs[r][cc];
            float4 w = ld4(&Wvp[(size_t)(hh * C_ + cc) * CP + o4]);
            a0 += s * w.x; a1 += s * w.y; a2 += s * w.z; a3 += s * w.w;
        }
        ushort4v vv; vv.x = f2bf(a0); vv.y = f2bf(a1); vv.z = f2bf(a2); vv.w = f2bf(a3);
        *reinterpret_cast<ushort4v*>(&vb[(size_t)(hh * NG + g0 + r) * VBS + o4]) = vv;
    }
    if (t < 32) {
        int r = t;
        float a = bv[hh * C_ + 128];
        for (int cc = 0; cc < C_; ++cc) a += Cs[r][cc] * Wvp[(size_t)(hh * C_ + cc) * CP + 128];
        ushort_t* vp = &vb[(size_t)(hh * NG + g0 + r) * VBS];
        ushort4v v1; v1.x = f2bf(a); v1.y = 0; v1.z = 0; v1.w = 0;
        *reinterpret_cast<ushort4v*>(vp + 128) = v1;
        ushort4v z; z.x = 0; z.y = 0; z.z = 0; z.w = 0;
        *reinterpret_cast<ushort4v*>(vp + 132) = z;
    }
}

// ---------------- K2: transpose vb [h][g][136] -> vT [h][n][g] (bf16) ----------------
__global__ __launch_bounds__(256) void k_vtrans(const ushort_t* __restrict__ vb,
                                                ushort_t* __restrict__ vTg) {
    __shared__ ushort_t T[136 * 72];
    const int t = threadIdx.x;
    const int g0 = blockIdx.x * 64;
    const int hh = blockIdx.y;
    for (int idx = t; idx < 64 * 17; idx += 256) {
        int row = idx / 17, c8 = (idx - row * 17) * 8;
        ushort8 v = *reinterpret_cast<const ushort8*>(&vb[(size_t)(hh * NG + g0 + row) * VBS + c8]);
#pragma unroll
        for (int i = 0; i < 8; ++i) T[(c8 + i) * 72 + row] = v[i];
    }
    __syncthreads();
    for (int idx = t; idx < VTN * 8; idx += 256) {
        int n = idx >> 3, gl = idx & 7;
        ushort8 o;
        if (n < 136) o = *reinterpret_cast<const ushort8*>(&T[n * 72 + gl * 8]);
        else { o = ushort8{0,0,0,0,0,0,0,0}; }
        *reinterpret_cast<ushort8*>(&vTg[(size_t)(hh * VTN + n) * NG + g0 + gl * 8]) = o;
    }
}

// ---------------- K3: attention — scalar QK/softmax + MFMA bf16 PV ----------------
__global__ __launch_bounds__(256) void k_attn(
    const float* __restrict__ qg, const float* __restrict__ kg,
    const ushort_t* __restrict__ vTg,
    const int* __restrict__ adj, const int* __restrict__ nodes_b, const int* __restrict__ nodes_n,
    float* __restrict__ hp) {
    __shared__ alignas(16) float Ks[64 * 20];
    __shared__ alignas(16) ushort_t Vt[VTN * 72];
    __shared__ alignas(16) ushort_t Pb[16 * 72];
    __shared__ float Lrow[16];
    __shared__ int Nrow[16];
    const int t = threadIdx.x;
    const int m0 = blockIdx.x * 16;
    const int hh = blockIdx.y;
    const int b = nodes_b[m0];
    if (t < 16) Nrow[t] = nodes_n[m0 + t];
    __syncthreads();
    const int r = t >> 4, cl = t & 15;
    float qreg[16];
    {
        const float* qp = &qg[(size_t)(hh * NG + b * N_ + Nrow[r]) * K_];
#pragma unroll
        for (int w4 = 0; w4 < 16; w4 += 4) {
            float4 qq = ld4(qp + w4);
            qreg[w4] = qq.x; qreg[w4 + 1] = qq.y; qreg[w4 + 2] = qq.z; qreg[w4 + 3] = qq.w;
        }
    }
    const int* adjrow = &adj[(size_t)Nrow[r] * N_];
    const int lane = t & 63, w = t >> 6;
    const int am = lane & 15, aq = lane >> 4;
    f32x4 accv[5];
#pragma unroll
    for (int s = 0; s < 5; ++s) accv[s] = f32x4{0.f, 0.f, 0.f, 0.f};
    float lsum = 0.f;

    for (int ct = 0; ct < 16; ++ct) {
        const int c0 = ct * 64;
        __syncthreads();
        {
            int row = t >> 2, k4 = (t & 3) * 4;
            st4(&Ks[row * 20 + k4], ld4(&kg[(size_t)(hh * NG + b * N_ + c0 + row) * K_ + k4]));
        }
        for (int idx = t; idx < VTN * 8; idx += 256) {
            int n = idx >> 3, l8 = idx & 7;
            *reinterpret_cast<ushort8*>(&Vt[n * 72 + l8 * 8]) =
                *reinterpret_cast<const ushort8*>(&vTg[(size_t)(hh * VTN + n) * NG + b * N_ + c0 + l8 * 8]);
        }
        __syncthreads();
#pragma unroll
        for (int j = 0; j < 4; ++j) {
            int c = cl + 16 * j;
            const float* kc = &Ks[c * 20];
            float4 k0 = ld4(kc), k1 = ld4(kc + 4), k2 = ld4(kc + 8), k3 = ld4(kc + 12);
            float dot = qreg[0]*k0.x + qreg[1]*k0.y + qreg[2]*k0.z + qreg[3]*k0.w
                      + qreg[4]*k1.x + qreg[5]*k1.y + qreg[6]*k1.z + qreg[7]*k1.w
                      + qreg[8]*k2.x + qreg[9]*k2.y + qreg[10]*k2.z + qreg[11]*k2.w
                      + qreg[12]*k3.x + qreg[13]*k3.y + qreg[14]*k3.z + qreg[15]*k3.w;
            float s = dot * 0.25f;
            s = (s >= 0.f) ? s : 0.2f * s;
            float p = adjrow[c0 + c] ? __expf(s) : 0.f;
            lsum += p;
            Pb[r * 72 + c] = f2bf(p);
        }
        __syncthreads();
#pragma unroll
        for (int s = 0; s < 5; ++s) {
            int u = 4 * s + w;
            if (u < 18) {
                int nt = u >> 1, kh = u & 1;
                short8 af = *reinterpret_cast<const short8*>(&Pb[am * 72 + kh * 32 + aq * 8]);
                short8 bfr = *reinterpret_cast<const short8*>(&Vt[(nt * 16 + am) * 72 + kh * 32 + aq * 8]);
                accv[s] = __builtin_amdgcn_mfma_f32_16x16x32_bf16(af, bfr, accv[s], 0, 0, 0);
            }
        }
    }
    lsum += __shfl_xor(lsum, 1);
    lsum += __shfl_xor(lsum, 2);
    lsum += __shfl_xor(lsum, 4);
    lsum += __shfl_xor(lsum, 8);
    if (cl == 0) Lrow[r] = lsum;
    __syncthreads();
    float* Ored = reinterpret_cast<float*>(Vt);
    if (w & 1) {
#pragma unroll
        for (int s = 0; s < 5; ++s) {
            int u = 4 * s + w;
            if (u < 18) {
                int nt = u >> 1;
#pragma unroll
                for (int i = 0; i < 4; ++i)
                    Ored[(aq * 4 + i) * 160 + nt * 16 + am] = accv[s][i];
            }
        }
    }
    if (t < 16) Lrow[t] = (Lrow[t] > 0.f) ? 1.f / Lrow[t] : 0.f;
    __syncthreads();
    if (!(w & 1)) {
#pragma unroll
        for (int s = 0; s < 5; ++s) {
            int u = 4 * s + w;
            if (u < 18) {
                int nt = u >> 1;
                int col = nt * 16 + am;
                if (col < C_) {
#pragma unroll
                    for (int i = 0; i < 4; ++i) {
                        int row = aq * 4 + i;
                        float val = (accv[s][i] + Ored[row * 160 + col]) * Lrow[row];
                        hp[(size_t)(m0 + row) * 516 + hh * C_ + col] = val;
                    }
                }
            }
        }
    }
}

// ---------------- K4: node MLP + skip -> cpost[M][CP]; 16-row tiles ----------------
__global__ __launch_bounds__(256) void k_mlp(
    const float* __restrict__ hp,
    const float* __restrict__ W1p, const float* __restrict__ b1,
    const float* __restrict__ W2p, const float* __restrict__ b2,
    const float* __restrict__ x, const float* __restrict__ h,
    const int* __restrict__ nb, const int* __restrict__ nn,
    float* __restrict__ cpost) {
    __shared__ float T[CP][20];
    const int t = threadIdx.x;
    const int m0 = blockIdx.x * 16;
    const int r0 = (t >> 5) * 2;
    const int o0 = (t & 31) * 4;
    const int rX = (t < 64) ? (t >> 2) : 0;
    const int oX = 128 + (t & 3);
    float acc[2][4] = {{0.f}};
    float accX = 0.f;
    for (int chunk = 0; chunk < 4; ++chunk) {
        const int kc = chunk * 132;
        const int csz = (chunk < 3) ? 132 : 120;
        __syncthreads();
        for (int idx = t; idx < 16 * 33; idx += 256) {
            int rr = idx / 33, i4 = (idx - rr * 33) * 4;
            if (i4 + 3 < csz) {
                float4 v4 = ld4(&hp[(size_t)(m0 + rr) * 516 + kc + i4]);
                T[i4 + 0][rr] = v4.x; T[i4 + 1][rr] = v4.y;
                T[i4 + 2][rr] = v4.z; T[i4 + 3][rr] = v4.w;
            }
        }
        __syncthreads();
        for (int k = 0; k < csz; ++k) {
            float2 a2 = ld2(&T[k][r0]);
            float4 w4 = ld4(&W1p[(size_t)(kc + k) * CP + o0]);
            const float* ap = (const float*)&a2;
            const float* wp = (const float*)&w4;
#pragma unroll
            for (int ri = 0; ri < 2; ++ri)
#pragma unroll
                for (int oi = 0; oi < 4; ++oi) acc[ri][oi] += ap[ri] * wp[oi];
            if (t < 64) accX += T[k][rX] * W1p[(size_t)(kc + k) * CP + oX];
        }
    }
    __syncthreads();
#pragma unroll
    for (int oi = 0; oi < 4; ++oi) {
        int o = o0 + oi;
        float bb = b1[o];
        st2(&T[o][r0], make_float2(fmaxf(acc[0][oi] + bb, 0.f), fmaxf(acc[1][oi] + bb, 0.f)));
    }
    if (t < 64) T[oX][rX] = (oX == 128) ? fmaxf(accX + b1[128], 0.f) : 0.f;
    __syncthreads();
    float acc2[2][4] = {{0.f}};
    float accX2 = 0.f;
    for (int k = 0; k < C_; ++k) {
        float2 a2 = ld2(&T[k][r0]);
        float4 w4 = ld4(&W2p[(size_t)k * CP + o0]);
        const float* ap = (const float*)&a2;
        const float* wp = (const float*)&w4;
#pragma unroll
        for (int ri = 0; ri < 2; ++ri)
#pragma unroll
            for (int oi = 0; oi < 4; ++oi) acc2[ri][oi] += ap[ri] * wp[oi];
        if (t < 64) accX2 += T[k][rX] * W2p[(size_t)k * CP + oX];
    }
#pragma unroll
    for (int ri = 0; ri < 2; ++ri) {
        int m = m0 + r0 + ri;
        int b = nb[m], n = nn[m];
        const float* xr = &x[(b * N_ + n) * 65];
        const float* hr = &h[(b * N_ + n) * D_];
        float o4[4];
#pragma unroll
        for (int oi = 0; oi < 4; ++oi) {
            int o = o0 + oi;
            float sk = (o < 65) ? xr[o] : hr[o - 65];
            o4[oi] = acc2[ri][oi] + b2[o] + sk;
        }
        st4(&cpost[(size_t)m * CP + o0], make_float4(o4[0], o4[1], o4[2], o4[3]));
    }
    if (t < 64) {
        int m = m0 + rX;
        if (oX == 128) {
            int b = nb[m], n = nn[m];
            cpost[(size_t)m * CP + 128] = accX2 + b2[128] + h[(b * N_ + n) * D_ + 63];
        } else {
            cpost[(size_t)m * CP + oX] = 0.f;
        }
    }
}

// ---------------- K5a: build A[m][KT] bf16 = qv[m][d]*src[m][i] (+bias slots qv) ----------------
__global__ __launch_bounds__(256) void k_arow(const float* __restrict__ src,
                                              const float* __restrict__ qv,
                                              ushort_t* __restrict__ A) {
    __shared__ float sq[CP];
    __shared__ float qs[QV_];
    const int t = threadIdx.x;
    const int m = blockIdx.x;
    if (t < CP) sq[t] = src[(size_t)m * CP + t];
    if (t >= 224) qs[t - 224] = qv[m * QV_ + (t - 224)];
    __syncthreads();
    ushort_t* Ar = A + (size_t)m * KT;
    for (int k = t; k < 4224; k += 256) {
        int d = k / 132, i = k - d * 132;
        Ar[k] = f2bf(qs[d] * sq[i]);
    }
    if (t < QV_) Ar[4224 + t] = f2bf(qs[t]);
}

// ---------------- K5b: hyper GEMM part[z][M][NN] = A-chunk @ WT^T ----------------
template<int NN>
__global__ __launch_bounds__(256) void k_gemm(const ushort_t* __restrict__ A,
                                              const ushort_t* __restrict__ WT,
                                              float* __restrict__ part) {
    const int t = threadIdx.x;
    const int m0 = blockIdx.x * 16;
    const int z = blockIdx.y;
    const int lane = t & 63, w = t >> 6;
    const int am = lane & 15, aq = lane >> 4;
    constexpr int NTpW = NN / 64;            // n-tiles per wave
    const int ktb = z * 34;
    const int kte = (ktb + 34 < NKT) ? ktb + 34 : NKT;
    f32x4 acc[NTpW];
#pragma unroll
    for (int j = 0; j < NTpW; ++j) acc[j] = f32x4{0.f, 0.f, 0.f, 0.f};
    const ushort_t* Ar = A + (size_t)(m0 + am) * KT;
    for (int kt = ktb; kt < kte; ++kt) {
        const int ko = kt * 32 + aq * 8;
        short8 af = *reinterpret_cast<const short8*>(Ar + ko);
#pragma unroll
        for (int j = 0; j < NTpW; ++j) {
            int nt = w + 4 * j;
            short8 bf = *reinterpret_cast<const short8*>(WT + (size_t)(nt * 16 + am) * KT + ko);
            acc[j] = __builtin_amdgcn_mfma_f32_16x16x32_bf16(af, bf, acc[j], 0, 0, 0);
        }
    }
#pragma unroll
    for (int j = 0; j < NTpW; ++j) {
        int n = (w + 4 * j) * 16 + am;
#pragma unroll
        for (int i = 0; i < 4; ++i) {
            int m = m0 + aq * 4 + i;
            part[((size_t)z * M_ + m) * NN + n] = acc[j][i];
        }
    }
}

// ---------------- K5c: build cin[M][CP] = [x_sel, sigmoid(r)*h_sel, 0pad] ----------------
__global__ void k_build_cin(const float* __restrict__ x, const float* __restrict__ h,
                            const int* __restrict__ nb, const int* __restrict__ nn,
                            const float* __restrict__ pru, float* __restrict__ cin) {
    int idx = blockIdx.x * 256 + threadIdx.x;
    if (idx >= M_ * CP) return;
    int m = idx / CP, i = idx - m * CP;
    int b = nb[m], n = nn[m];
    float val;
    if (i < 65) val = x[(b * N_ + n) * 65 + i];
    else if (i < C_) {
        int o = i - 65;
        const size_t S = (size_t)M_ * 128;
        size_t base = (size_t)m * 128 + o;
        float s = pru[base] + pru[S + base] + pru[2 * S + base] + pru[3 * S + base];
        float rv = 1.f / (1.f + __expf(-s));
        val = rv * h[(b * N_ + n) * D_ + o];
    } else val = 0.f;
    cin[idx] = val;
}

// ---------------- K5d: final gate ----------------
__global__ void k_final(const float* __restrict__ pru, const float* __restrict__ pc,
                        const float* __restrict__ cin, float* __restrict__ out) {
    int idx = blockIdx.x * 256 + threadIdx.x;
    if (idx >= M_ * D_) return;
    int m = idx >> 6, o = idx & 63;
    const size_t Su = (size_t)M_ * 128;
    size_t bu = (size_t)m * 128 + 64 + o;
    float su = pru[bu] + pru[Su + bu] + pru[2 * Su + bu] + pru[3 * Su + bu];
    float uv = 1.f / (1.f + __expf(-su));
    const size_t Sc = (size_t)M_ * 64;
    size_t bc = (size_t)m * 64 + o;
    float sc = pc[bc] + pc[Sc + bc] + pc[2 * Sc + bc] + pc[3 * Sc + bc];
    float cand = tanhf(sc);
    float hn = cin[(size_t)m * CP + 65 + o];
    out[idx] = (1.f - uv) * hn + uv * cand;
}

extern "C" void kernel_launch(void* const* d_in, const int* in_sizes, int n_in,
                              void* d_out, int out_size, void* d_ws, size_t ws_size,
                              hipStream_t stream) {
    const float* x   = (const float*)d_in[0];
    const float* h   = (const float*)d_in[1];
    const float* qv  = (const float*)d_in[2];
    const int*   adj = (const int*)d_in[3];
    const int*   nb  = (const int*)d_in[4];
    const int*   nn  = (const int*)d_in[5];
    const float* Wq  = (const float*)d_in[6];
    const float* bq  = (const float*)d_in[7];
    const float* Wk  = (const float*)d_in[8];
    const float* bk  = (const float*)d_in[9];
    const float* Wv  = (const float*)d_in[10];
    const float* bv  = (const float*)d_in[11];
    const float* W1  = (const float*)d_in[12];
    const float* b1  = (const float*)d_in[13];
    const float* W2  = (const float*)d_in[14];
    const float* b2  = (const float*)d_in[15];
    const float* Wr  = (const float*)d_in[16];
    const float* br  = (const float*)d_in[17];
    const float* Wu  = (const float*)d_in[18];
    const float* bu  = (const float*)d_in[19];
    const float* Wc  = (const float*)d_in[20];
    const float* bc  = (const float*)d_in[21];
    float* ws = (float*)d_ws;
    float* out = (float*)d_out;

    float* Wvp   = ws + o_Wvp;
    float* qo    = ws + o_q;
    float* ko    = ws + o_k;
    ushort_t* vb  = (ushort_t*)(ws + o_vb);
    ushort_t* vTg = (ushort_t*)(ws + o_vT);
    float* hp    = ws + o_hp;
    float* cpost = ws + o_cpost;
    float* W1p   = ws + o_W1p;
    float* W2p   = ws + o_W2p;
    ushort_t* wtru = (ushort_t*)(ws + o_wtru);
    ushort_t* wtc  = (ushort_t*)(ws + o_wtc);
    ushort_t* Abuf = (ushort_t*)(ws + o_A);
    float* pru   = ws + o_pru;
    float* pc    = ws + o_pc2;
    float* cin   = ws + o_cin;

    const int prep_tot = H_ * C_ * CP + 516 * CP + C_ * CP;
    k_prep<<<(prep_tot + 255) / 256, 256, 0, stream>>>(Wv, Wvp, W1, W1p, W2, W2p);
    k_wt<<<(192 * KT + 255) / 256, 256, 0, stream>>>(Wr, br, Wu, bu, Wc, bc, wtru, wtc);
    k_qkv<<<dim3(NG / 32, H_), 256, 0, stream>>>(x, h, Wq, bq, Wk, bk, Wvp, bv, qo, ko, vb);
    k_vtrans<<<dim3(NG / 64, H_), 256, 0, stream>>>(vb, vTg);
    k_attn<<<dim3(M_ / 16, H_), 256, 0, stream>>>(qo, ko, vTg, adj, nb, nn, hp);
    k_mlp<<<M_ / 16, 256, 0, stream>>>(hp, W1p, b1, W2p, b2, x, h, nb, nn, cpost);
    k_arow<<<M_, 256, 0, stream>>>(cpost, qv, Abuf);
    k_gemm<128><<<dim3(M_ / 16, 4), 256, 0, stream>>>(Abuf, wtru, pru);
    k_build_cin<<<(M_ * CP) / 256, 256, 0, stream>>>(x, h, nb, nn, pru, cin);
    k_arow<<<M_, 256, 0, stream>>>(cin, qv, Abuf);
    k_gemm<64><<<dim3(M_ / 16, 4), 256, 0, stream>>>(Abuf, wtc, pc);
    k_final<<<(M_ * D_) / 256, 256, 0, stream>>>(pru, pc, cin, out);
}

// Round 7
// 373.777 us; speedup vs baseline: 1.8789x; 1.2787x over previous
//
#include <hip/hip_runtime.h>

#define DEVINL __device__ __forceinline__

typedef unsigned short ushort_t;
typedef __attribute__((ext_vector_type(8))) short short8;
typedef __attribute__((ext_vector_type(8))) unsigned short ushort8;
typedef __attribute__((ext_vector_type(4))) unsigned short ushort4v;
typedef __attribute__((ext_vector_type(4))) float f32x4;

constexpr int B_ = 8, N_ = 1024, D_ = 64, H_ = 4, QV_ = 32;
constexpr int C_ = 129, K_ = 16, M_ = 4096;
constexpr int CP = 132;              // padded C (multiple of 4)
constexpr int NG = B_ * N_;          // 8192 nodes total
constexpr int VBS = 136;             // vb bf16 row stride
constexpr int VTN = 144;             // vT padded n-dim (9 MFMA n-tiles)
constexpr int KT = 4256;             // hyper GEMM K: 32*132 + 32 bias slots (133 tiles of 32)
constexpr int NKT = 133;
constexpr int HPS = 544;             // hpb bf16 row stride (516 padded to 17*32)

// ---- workspace layout (float offsets) ----
constexpr size_t o_Wvp   = 0;                                   // H*C*CP
constexpr size_t o_q     = o_Wvp + (size_t)H_ * C_ * CP;        // H*NG*K
constexpr size_t o_k     = o_q   + (size_t)H_ * NG * K_;        // H*NG*K
constexpr size_t o_vb    = o_k   + (size_t)H_ * NG * K_;        // H*NG*136 ushort
constexpr size_t o_vT    = o_vb  + (size_t)H_ * NG * VBS / 2;   // H*144*NG ushort
constexpr size_t o_hpb   = o_vT  + (size_t)H_ * VTN * NG / 2;   // M*544 ushort
constexpr size_t o_cpost = o_hpb + (size_t)M_ * HPS / 2;        // M*CP fp32
constexpr size_t o_W1T   = o_cpost + (size_t)M_ * CP;           // 144*544 ushort
constexpr size_t o_W2T   = o_W1T + (size_t)144 * HPS / 2;       // 144*160 ushort
constexpr size_t o_wtru  = o_W2T + (size_t)144 * 160 / 2;       // 128*KT ushort
constexpr size_t o_wtc   = o_wtru + (size_t)128 * KT / 2;       // 64*KT ushort
constexpr size_t o_A     = o_wtc + (size_t)64 * KT / 2;         // M*KT ushort
constexpr size_t o_pru   = o_A + (size_t)M_ * KT / 2;           // 4*M*128 fp32
constexpr size_t o_pc2   = o_pru + (size_t)4 * M_ * 128;        // 4*M*64 fp32
// aliases (lifetimes disjoint): cin overlays q (and spills into k; both dead post-attn)
constexpr size_t o_cin = o_q;      // M*CP

DEVINL float4 ld4(const float* p) { return *reinterpret_cast<const float4*>(p); }
DEVINL float2 ld2(const float* p) { return *reinterpret_cast<const float2*>(p); }
DEVINL void st4(float* p, float4 v) { *reinterpret_cast<float4*>(p) = v; }
DEVINL void st2(float* p, float2 v) { *reinterpret_cast<float2*>(p) = v; }
DEVINL ushort_t f2bf(float f) {           // RNE fp32->bf16
    unsigned int u = __float_as_uint(f);
    u += 0x7FFFu + ((u >> 16) & 1u);
    return (ushort_t)(u >> 16);
}

// ---------------- K0: pad Wv into [H][C][CP] ----------------
__global__ void k_prep(const float* __restrict__ Wv, float* __restrict__ Wvp) {
    int idx = blockIdx.x * 256 + threadIdx.x;
    const int totV = H_ * C_ * CP;
    if (idx >= totV) return;
    int hh = idx / (C_ * CP); int rem = idx - hh * C_ * CP;
    int cc = rem / CP;        int o  = rem - cc * CP;
    Wvp[idx] = (o < C_) ? Wv[(hh * C_ + cc) * C_ + o] : 0.f;
}

// ---------------- K0a: build W1T[144][544], W2T[144][160] bf16 (transposed, zero-padded) --------
__global__ void k_wmlp(const float* __restrict__ W1, const float* __restrict__ W2,
                       ushort_t* __restrict__ W1T, ushort_t* __restrict__ W2T) {
    int idx = blockIdx.x * 256 + threadIdx.x;
    const int tot1 = 144 * HPS;
    const int tot2 = 144 * 160;
    if (idx < tot1) {
        int o = idx / HPS, k = idx - o * HPS;
        float v = (o < C_ && k < 516) ? W1[(size_t)k * C_ + o] : 0.f;
        W1T[idx] = f2bf(v);
    } else if (idx < tot1 + tot2) {
        int j = idx - tot1;
        int o = j / 160, k = j - o * 160;
        float v = (o < C_ && k < C_) ? W2[(size_t)k * C_ + o] : 0.f;
        W2T[j] = f2bf(v);
    }
}

// ---------------- K0b: build WT_ru[128][KT], WT_c[64][KT] bf16 ----------------
__global__ void k_wt(const float* __restrict__ Wr, const float* __restrict__ br,
                     const float* __restrict__ Wu, const float* __restrict__ bu,
                     const float* __restrict__ Wc, const float* __restrict__ bc,
                     ushort_t* __restrict__ wtru, ushort_t* __restrict__ wtc) {
    int idx = blockIdx.x * 256 + threadIdx.x;
    const int tot = 192 * KT;
    if (idx >= tot) return;
    int row = idx / KT, k = idx - row * KT;
    float v;
    if (k >= 4224) {
        int d = k - 4224;
        if (row < 64) v = br[d * 64 + row];
        else if (row < 128) v = bu[d * 64 + row - 64];
        else v = bc[d * 64 + row - 128];
    } else {
        int d = k / 132, i = k - d * 132;
        if (i >= 129) v = 0.f;
        else if (row < 64) v = Wr[(size_t)(d * 129 + i) * 64 + row];
        else if (row < 128) v = Wu[(size_t)(d * 129 + i) * 64 + row - 64];
        else v = Wc[(size_t)(d * 129 + i) * 64 + row - 128];
    }
    if (row < 128) wtru[(size_t)row * KT + k] = f2bf(v);
    else wtc[(size_t)(row - 128) * KT + k] = f2bf(v);
}

// ---------------- K1: combined -> q,k fp32; v -> bf16 [h][g][136] ----------------
__global__ __launch_bounds__(256) void k_qkv(
    const float* __restrict__ x, const float* __restrict__ h,
    const float* __restrict__ Wq, const float* __restrict__ bq,
    const float* __restrict__ Wk, const float* __restrict__ bk,
    const float* __restrict__ Wvp, const float* __restrict__ bv,
    float* __restrict__ qo, float* __restrict__ ko, ushort_t* __restrict__ vb) {
    __shared__ float Cs[32][CP];
    const int t = threadIdx.x;
    const int g0 = blockIdx.x * 32;
    const int hh = blockIdx.y;
    for (int idx = t; idx < 32 * C_; idx += 256) {
        int r = idx / C_, cc = idx - r * C_;
        int g = g0 + r; int b = g >> 10, n = g & (N_ - 1);
        Cs[r][cc] = (cc < 65) ? x[(b * N_ + n) * 65 + cc]
                              : h[(b * N_ + n) * D_ + (cc - 65)];
    }
    __syncthreads();
    {
        const int r = (t & 127) >> 2, kb = (t & 3) * 4;
        const float* W = (t < 128) ? Wq : Wk;
        const float* bb = (t < 128) ? bq : bk;
        float a[4];
#pragma unroll
        for (int j = 0; j < 4; ++j) a[j] = bb[hh * K_ + kb + j];
        for (int cc = 0; cc < C_; ++cc) {
            float s = Cs[r][cc];
            float4 w = ld4(&W[(size_t)(hh * C_ + cc) * K_ + kb]);
            a[0] += s * w.x; a[1] += s * w.y; a[2] += s * w.z; a[3] += s * w.w;
        }
        float* dst = (t < 128) ? qo : ko;
        st4(&dst[(size_t)(hh * NG + g0 + r) * K_ + kb], make_float4(a[0], a[1], a[2], a[3]));
    }
    for (int jj = 0; jj < 4; ++jj) {
        int idx = t + 256 * jj;
        int r = idx >> 5, o4 = (idx & 31) * 4;
        float a0 = bv[hh * C_ + o4 + 0], a1 = bv[hh * C_ + o4 + 1],
              a2 = bv[hh * C_ + o4 + 2], a3 = bv[hh * C_ + o4 + 3];
        for (int cc = 0; cc < C_; ++cc) {
            float s = Cs[r][cc];
            float4 w = ld4(&Wvp[(size_t)(hh * C_ + cc) * CP + o4]);
            a0 += s * w.x; a1 += s * w.y; a2 += s * w.z; a3 += s * w.w;
        }
        ushort4v vv; vv.x = f2bf(a0); vv.y = f2bf(a1); vv.z = f2bf(a2); vv.w = f2bf(a3);
        *reinterpret_cast<ushort4v*>(&vb[(size_t)(hh * NG + g0 + r) * VBS + o4]) = vv;
    }
    if (t < 32) {
        int r = t;
        float a = bv[hh * C_ + 128];
        for (int cc = 0; cc < C_; ++cc) a += Cs[r][cc] * Wvp[(size_t)(hh * C_ + cc) * CP + 128];
        ushort_t* vp = &vb[(size_t)(hh * NG + g0 + r) * VBS];
        ushort4v v1; v1.x = f2bf(a); v1.y = 0; v1.z = 0; v1.w = 0;
        *reinterpret_cast<ushort4v*>(vp + 128) = v1;
        ushort4v z; z.x = 0; z.y = 0; z.z = 0; z.w = 0;
        *reinterpret_cast<ushort4v*>(vp + 132) = z;
    }
}

// ---------------- K2: transpose vb [h][g][136] -> vT [h][n][g] (bf16) ----------------
__global__ __launch_bounds__(256) void k_vtrans(const ushort_t* __restrict__ vb,
                                                ushort_t* __restrict__ vTg) {
    __shared__ ushort_t T[136 * 72];
    const int t = threadIdx.x;
    const int g0 = blockIdx.x * 64;
    const int hh = blockIdx.y;
    for (int idx = t; idx < 64 * 17; idx += 256) {
        int row = idx / 17, c8 = (idx - row * 17) * 8;
        ushort8 v = *reinterpret_cast<const ushort8*>(&vb[(size_t)(hh * NG + g0 + row) * VBS + c8]);
#pragma unroll
        for (int i = 0; i < 8; ++i) T[(c8 + i) * 72 + row] = v[i];
    }
    __syncthreads();
    for (int idx = t; idx < VTN * 8; idx += 256) {
        int n = idx >> 3, gl = idx & 7;
        ushort8 o;
        if (n < 136) o = *reinterpret_cast<const ushort8*>(&T[n * 72 + gl * 8]);
        else { o = ushort8{0,0,0,0,0,0,0,0}; }
        *reinterpret_cast<ushort8*>(&vTg[(size_t)(hh * VTN + n) * NG + g0 + gl * 8]) = o;
    }
}

// ---------------- K3: attention — scalar QK/softmax + MFMA bf16 PV -> hpb bf16 ----------------
__global__ __launch_bounds__(256) void k_attn(
    const float* __restrict__ qg, const float* __restrict__ kg,
    const ushort_t* __restrict__ vTg,
    const int* __restrict__ adj, const int* __restrict__ nodes_b, const int* __restrict__ nodes_n,
    ushort_t* __restrict__ hpb) {
    __shared__ alignas(16) float Ks[64 * 20];
    __shared__ alignas(16) ushort_t Vt[VTN * 72];
    __shared__ alignas(16) ushort_t Pb[16 * 72];
    __shared__ float Lrow[16];
    __shared__ int Nrow[16];
    const int t = threadIdx.x;
    const int m0 = blockIdx.x * 16;
    const int hh = blockIdx.y;
    const int b = nodes_b[m0];
    if (t < 16) Nrow[t] = nodes_n[m0 + t];
    __syncthreads();
    const int r = t >> 4, cl = t & 15;
    float qreg[16];
    {
        const float* qp = &qg[(size_t)(hh * NG + b * N_ + Nrow[r]) * K_];
#pragma unroll
        for (int w4 = 0; w4 < 16; w4 += 4) {
            float4 qq = ld4(qp + w4);
            qreg[w4] = qq.x; qreg[w4 + 1] = qq.y; qreg[w4 + 2] = qq.z; qreg[w4 + 3] = qq.w;
        }
    }
    const int* adjrow = &adj[(size_t)Nrow[r] * N_];
    const int lane = t & 63, w = t >> 6;
    const int am = lane & 15, aq = lane >> 4;
    f32x4 accv[5];
#pragma unroll
    for (int s = 0; s < 5; ++s) accv[s] = f32x4{0.f, 0.f, 0.f, 0.f};
    float lsum = 0.f;

    for (int ct = 0; ct < 16; ++ct) {
        const int c0 = ct * 64;
        __syncthreads();
        {
            int row = t >> 2, k4 = (t & 3) * 4;
            st4(&Ks[row * 20 + k4], ld4(&kg[(size_t)(hh * NG + b * N_ + c0 + row) * K_ + k4]));
        }
        for (int idx = t; idx < VTN * 8; idx += 256) {
            int n = idx >> 3, l8 = idx & 7;
            *reinterpret_cast<ushort8*>(&Vt[n * 72 + l8 * 8]) =
                *reinterpret_cast<const ushort8*>(&vTg[(size_t)(hh * VTN + n) * NG + b * N_ + c0 + l8 * 8]);
        }
        __syncthreads();
#pragma unroll
        for (int j = 0; j < 4; ++j) {
            int c = cl + 16 * j;
            const float* kc = &Ks[c * 20];
            float4 k0 = ld4(kc), k1 = ld4(kc + 4), k2 = ld4(kc + 8), k3 = ld4(kc + 12);
            float dot = qreg[0]*k0.x + qreg[1]*k0.y + qreg[2]*k0.z + qreg[3]*k0.w
                      + qreg[4]*k1.x + qreg[5]*k1.y + qreg[6]*k1.z + qreg[7]*k1.w
                      + qreg[8]*k2.x + qreg[9]*k2.y + qreg[10]*k2.z + qreg[11]*k2.w
                      + qreg[12]*k3.x + qreg[13]*k3.y + qreg[14]*k3.z + qreg[15]*k3.w;
            float s = dot * 0.25f;
            s = (s >= 0.f) ? s : 0.2f * s;
            float p = adjrow[c0 + c] ? __expf(s) : 0.f;
            lsum += p;
            Pb[r * 72 + c] = f2bf(p);
        }
        __syncthreads();
#pragma unroll
        for (int s = 0; s < 5; ++s) {
            int u = 4 * s + w;
            if (u < 18) {
                int nt = u >> 1, kh = u & 1;
                short8 af = *reinterpret_cast<const short8*>(&Pb[am * 72 + kh * 32 + aq * 8]);
                short8 bfr = *reinterpret_cast<const short8*>(&Vt[(nt * 16 + am) * 72 + kh * 32 + aq * 8]);
                accv[s] = __builtin_amdgcn_mfma_f32_16x16x32_bf16(af, bfr, accv[s], 0, 0, 0);
            }
        }
    }
    lsum += __shfl_xor(lsum, 1);
    lsum += __shfl_xor(lsum, 2);
    lsum += __shfl_xor(lsum, 4);
    lsum += __shfl_xor(lsum, 8);
    if (cl == 0) Lrow[r] = lsum;
    __syncthreads();
    float* Ored = reinterpret_cast<float*>(Vt);
    if (w & 1) {
#pragma unroll
        for (int s = 0; s < 5; ++s) {
            int u = 4 * s + w;
            if (u < 18) {
                int nt = u >> 1;
#pragma unroll
                for (int i = 0; i < 4; ++i)
                    Ored[(aq * 4 + i) * 160 + nt * 16 + am] = accv[s][i];
            }
        }
    }
    if (t < 16) Lrow[t] = (Lrow[t] > 0.f) ? 1.f / Lrow[t] : 0.f;
    __syncthreads();
    if (!(w & 1)) {
#pragma unroll
        for (int s = 0; s < 5; ++s) {
            int u = 4 * s + w;
            if (u < 18) {
                int nt = u >> 1;
                int col = nt * 16 + am;
                if (col < C_) {
#pragma unroll
                    for (int i = 0; i < 4; ++i) {
                        int row = aq * 4 + i;
                        float val = (accv[s][i] + Ored[row * 160 + col]) * Lrow[row];
                        hpb[(size_t)(m0 + row) * HPS + hh * C_ + col] = f2bf(val);
                    }
                }
            }
        }
    }
    if (hh == 3) {   // zero pad cols 516..543
        for (int idx = t; idx < 16 * 28; idx += 256) {
            int rr = idx / 28, cc = 516 + (idx - rr * 28);
            hpb[(size_t)(m0 + rr) * HPS + cc] = 0;
        }
    }
}

// ---------------- K4: node MLP (MFMA) + skip -> cpost[M][CP] ----------------
// 16-row blocks, grid 256. GEMM1: [16x544]@[544x144]; GEMM2: [16x160]@[160x144].
__global__ __launch_bounds__(256) void k_mlp(
    const ushort_t* __restrict__ hpb,
    const ushort_t* __restrict__ W1T, const float* __restrict__ b1,
    const ushort_t* __restrict__ W2T, const float* __restrict__ b2,
    const float* __restrict__ x, const float* __restrict__ h,
    const int* __restrict__ nb, const int* __restrict__ nn,
    float* __restrict__ cpost) {
    __shared__ alignas(16) ushort_t Hs[16 * 168];   // hidden bf16, row stride 168
    const int t = threadIdx.x;
    const int m0 = blockIdx.x * 16;
    const int lane = t & 63, w = t >> 6;
    const int am = lane & 15, aq = lane >> 4;
    f32x4 acc[3];
#pragma unroll
    for (int j = 0; j < 3; ++j) acc[j] = f32x4{0.f, 0.f, 0.f, 0.f};
    const ushort_t* Ar = hpb + (size_t)(m0 + am) * HPS;
    for (int kt = 0; kt < 17; ++kt) {
        short8 af = *reinterpret_cast<const short8*>(Ar + kt * 32 + aq * 8);
#pragma unroll
        for (int j = 0; j < 3; ++j) {
            int nt = w + 4 * j;
            if (nt < 9) {
                short8 bf = *reinterpret_cast<const short8*>(W1T + (size_t)(nt * 16 + am) * HPS + kt * 32 + aq * 8);
                acc[j] = __builtin_amdgcn_mfma_f32_16x16x32_bf16(af, bf, acc[j], 0, 0, 0);
            }
        }
    }
#pragma unroll
    for (int j = 0; j < 3; ++j) {
        int nt = w + 4 * j;
        if (nt < 9) {
            int col = nt * 16 + am;
            float bb = (col < C_) ? b1[col] : 0.f;
#pragma unroll
            for (int i = 0; i < 4; ++i) {
                int row = aq * 4 + i;
                float v = (col < C_) ? fmaxf(acc[j][i] + bb, 0.f) : 0.f;
                Hs[row * 168 + col] = f2bf(v);
            }
        }
    }
    { int row = t >> 4, cc = 144 + (t & 15); Hs[row * 168 + cc] = 0; }  // zero k=144..159
    __syncthreads();
    f32x4 acc2[3];
#pragma unroll
    for (int j = 0; j < 3; ++j) acc2[j] = f32x4{0.f, 0.f, 0.f, 0.f};
    for (int kt = 0; kt < 5; ++kt) {
        short8 af = *reinterpret_cast<const short8*>(&Hs[am * 168 + kt * 32 + aq * 8]);
#pragma unroll
        for (int j = 0; j < 3; ++j) {
            int nt = w + 4 * j;
            if (nt < 9) {
                short8 bf = *reinterpret_cast<const short8*>(W2T + (size_t)(nt * 16 + am) * 160 + kt * 32 + aq * 8);
                acc2[j] = __builtin_amdgcn_mfma_f32_16x16x32_bf16(af, bf, acc2[j], 0, 0, 0);
            }
        }
    }
#pragma unroll
    for (int j = 0; j < 3; ++j) {
        int nt = w + 4 * j;
        if (nt < 9) {
            int col = nt * 16 + am;
            if (col < C_) {
                float bb = b2[col];
#pragma unroll
                for (int i = 0; i < 4; ++i) {
                    int m = m0 + aq * 4 + i;
                    int b = nb[m], n = nn[m];
                    float sk = (col < 65) ? x[(b * N_ + n) * 65 + col]
                                          : h[(b * N_ + n) * D_ + (col - 65)];
                    cpost[(size_t)m * CP + col] = acc2[j][i] + bb + sk;
                }
            }
        }
    }
    if (t < 48) {
        int rr = t / 3, cc = 129 + (t - (t / 3) * 3);
        cpost[(size_t)(m0 + rr) * CP + cc] = 0.f;
    }
}

// ---------------- K5a: build A[m][KT] bf16 = qv[m][d]*src[m][i] (+bias slots qv) ----------------
__global__ __launch_bounds__(256) void k_arow(const float* __restrict__ src,
                                              const float* __restrict__ qv,
                                              ushort_t* __restrict__ A) {
    __shared__ float sq[CP];
    __shared__ float qs[QV_];
    const int t = threadIdx.x;
    const int m = blockIdx.x;
    if (t < CP) sq[t] = src[(size_t)m * CP + t];
    if (t >= 224) qs[t - 224] = qv[m * QV_ + (t - 224)];
    __syncthreads();
    ushort_t* Ar = A + (size_t)m * KT;
    for (int k = t; k < 4224; k += 256) {
        int d = k / 132, i = k - d * 132;
        Ar[k] = f2bf(qs[d] * sq[i]);
    }
    if (t < QV_) Ar[4224 + t] = f2bf(qs[t]);
}

// ---------------- K5b: hyper GEMM part[z][M][NN] = A-chunk @ WT^T ----------------
template<int NN>
__global__ __launch_bounds__(256) void k_gemm(const ushort_t* __restrict__ A,
                                              const ushort_t* __restrict__ WT,
                                              float* __restrict__ part) {
    const int t = threadIdx.x;
    const int m0 = blockIdx.x * 16;
    const int z = blockIdx.y;
    const int lane = t & 63, w = t >> 6;
    const int am = lane & 15, aq = lane >> 4;
    constexpr int NTpW = NN / 64;
    const int ktb = z * 34;
    const int kte = (ktb + 34 < NKT) ? ktb + 34 : NKT;
    f32x4 acc[NTpW];
#pragma unroll
    for (int j = 0; j < NTpW; ++j) acc[j] = f32x4{0.f, 0.f, 0.f, 0.f};
    const ushort_t* Ar = A + (size_t)(m0 + am) * KT;
    for (int kt = ktb; kt < kte; ++kt) {
        const int ko = kt * 32 + aq * 8;
        short8 af = *reinterpret_cast<const short8*>(Ar + ko);
#pragma unroll
        for (int j = 0; j < NTpW; ++j) {
            int nt = w + 4 * j;
            short8 bf = *reinterpret_cast<const short8*>(WT + (size_t)(nt * 16 + am) * KT + ko);
            acc[j] = __builtin_amdgcn_mfma_f32_16x16x32_bf16(af, bf, acc[j], 0, 0, 0);
        }
    }
#pragma unroll
    for (int j = 0; j < NTpW; ++j) {
        int n = (w + 4 * j) * 16 + am;
#pragma unroll
        for (int i = 0; i < 4; ++i) {
            int m = m0 + aq * 4 + i;
            part[((size_t)z * M_ + m) * NN + n] = acc[j][i];
        }
    }
}

// ---------------- K5c: build cin[M][CP] = [x_sel, sigmoid(r)*h_sel, 0pad] ----------------
__global__ void k_build_cin(const float* __restrict__ x, const float* __restrict__ h,
                            const int* __restrict__ nb, const int* __restrict__ nn,
                            const float* __restrict__ pru, float* __restrict__ cin) {
    int idx = blockIdx.x * 256 + threadIdx.x;
    if (idx >= M_ * CP) return;
    int m = idx / CP, i = idx - m * CP;
    int b = nb[m], n = nn[m];
    float val;
    if (i < 65) val = x[(b * N_ + n) * 65 + i];
    else if (i < C_) {
        int o = i - 65;
        const size_t S = (size_t)M_ * 128;
        size_t base = (size_t)m * 128 + o;
        float s = pru[base] + pru[S + base] + pru[2 * S + base] + pru[3 * S + base];
        float rv = 1.f / (1.f + __expf(-s));
        val = rv * h[(b * N_ + n) * D_ + o];
    } else val = 0.f;
    cin[idx] = val;
}

// ---------------- K5d: final gate ----------------
__global__ void k_final(const float* __restrict__ pru, const float* __restrict__ pc,
                        const float* __restrict__ cin, float* __restrict__ out) {
    int idx = blockIdx.x * 256 + threadIdx.x;
    if (idx >= M_ * D_) return;
    int m = idx >> 6, o = idx & 63;
    const size_t Su = (size_t)M_ * 128;
    size_t bu = (size_t)m * 128 + 64 + o;
    float su = pru[bu] + pru[Su + bu] + pru[2 * Su + bu] + pru[3 * Su + bu];
    float uv = 1.f / (1.f + __expf(-su));
    const size_t Sc = (size_t)M_ * 64;
    size_t bc = (size_t)m * 64 + o;
    float sc = pc[bc] + pc[Sc + bc] + pc[2 * Sc + bc] + pc[3 * Sc + bc];
    float cand = tanhf(sc);
    float hn = cin[(size_t)m * CP + 65 + o];
    out[idx] = (1.f - uv) * hn + uv * cand;
}

extern "C" void kernel_launch(void* const* d_in, const int* in_sizes, int n_in,
                              void* d_out, int out_size, void* d_ws, size_t ws_size,
                              hipStream_t stream) {
    const float* x   = (const float*)d_in[0];
    const float* h   = (const float*)d_in[1];
    const float* qv  = (const float*)d_in[2];
    const int*   adj = (const int*)d_in[3];
    const int*   nb  = (const int*)d_in[4];
    const int*   nn  = (const int*)d_in[5];
    const float* Wq  = (const float*)d_in[6];
    const float* bq  = (const float*)d_in[7];
    const float* Wk  = (const float*)d_in[8];
    const float* bk  = (const float*)d_in[9];
    const float* Wv  = (const float*)d_in[10];
    const float* bv  = (const float*)d_in[11];
    const float* W1  = (const float*)d_in[12];
    const float* b1  = (const float*)d_in[13];
    const float* W2  = (const float*)d_in[14];
    const float* b2  = (const float*)d_in[15];
    const float* Wr  = (const float*)d_in[16];
    const float* br  = (const float*)d_in[17];
    const float* Wu  = (const float*)d_in[18];
    const float* bu  = (const float*)d_in[19];
    const float* Wc  = (const float*)d_in[20];
    const float* bc  = (const float*)d_in[21];
    float* ws = (float*)d_ws;
    float* out = (float*)d_out;

    float* Wvp   = ws + o_Wvp;
    float* qo    = ws + o_q;
    float* ko    = ws + o_k;
    ushort_t* vb   = (ushort_t*)(ws + o_vb);
    ushort_t* vTg  = (ushort_t*)(ws + o_vT);
    ushort_t* hpb  = (ushort_t*)(ws + o_hpb);
    float* cpost = ws + o_cpost;
    ushort_t* W1T  = (ushort_t*)(ws + o_W1T);
    ushort_t* W2T  = (ushort_t*)(ws + o_W2T);
    ushort_t* wtru = (ushort_t*)(ws + o_wtru);
    ushort_t* wtc  = (ushort_t*)(ws + o_wtc);
    ushort_t* Abuf = (ushort_t*)(ws + o_A);
    float* pru   = ws + o_pru;
    float* pc    = ws + o_pc2;
    float* cin   = ws + o_cin;

    k_prep<<<(H_ * C_ * CP + 255) / 256, 256, 0, stream>>>(Wv, Wvp);
    k_wmlp<<<(144 * HPS + 144 * 160 + 255) / 256, 256, 0, stream>>>(W1, W2, W1T, W2T);
    k_wt<<<(192 * KT + 255) / 256, 256, 0, stream>>>(Wr, br, Wu, bu, Wc, bc, wtru, wtc);
    k_qkv<<<dim3(NG / 32, H_), 256, 0, stream>>>(x, h, Wq, bq, Wk, bk, Wvp, bv, qo, ko, vb);
    k_vtrans<<<dim3(NG / 64, H_), 256, 0, stream>>>(vb, vTg);
    k_attn<<<dim3(M_ / 16, H_), 256, 0, stream>>>(qo, ko, vTg, adj, nb, nn, hpb);
    k_mlp<<<M_ / 16, 256, 0, stream>>>(hpb, W1T, b1, W2T, b2, x, h, nb, nn, cpost);
    k_arow<<<M_, 256, 0, stream>>>(cpost, qv, Abuf);
    k_gemm<128><<<dim3(M_ / 16, 4), 256, 0, stream>>>(Abuf, wtru, pru);
    k_build_cin<<<(M_ * CP) / 256, 256, 0, stream>>>(x, h, nb, nn, pru, cin);
    k_arow<<<M_, 256, 0, stream>>>(cin, qv, Abuf);
    k_gemm<64><<<dim3(M_ / 16, 4), 256, 0, stream>>>(Abuf, wtc, pc);
    k_final<<<(M_ * D_) / 256, 256, 0, stream>>>(pru, pc, cin, out);
}

// Round 8
// 295.904 us; speedup vs baseline: 2.3733x; 1.2632x over previous
//
#include <hip/hip_runtime.h>

#define DEVINL __device__ __forceinline__

typedef unsigned short ushort_t;
typedef __attribute__((ext_vector_type(8))) short short8;
typedef __attribute__((ext_vector_type(8))) unsigned short ushort8;
typedef __attribute__((ext_vector_type(4))) float f32x4;

constexpr int B_ = 8, N_ = 1024, D_ = 64, H_ = 4, QV_ = 32;
constexpr int C_ = 129, K_ = 16, M_ = 4096;
constexpr int CP = 132;              // padded C
constexpr int NG = B_ * N_;          // 8192 nodes
constexpr int CBS = 160;             // cb row stride (5 k-tiles of 32; k=129 is bias-1.0 slot)
constexpr int VTN = 144;             // vT padded n-dim (9 MFMA n-tiles)
constexpr int KT = 4256;             // hyper GEMM K (133 tiles of 32)
constexpr int NKT = 133;
constexpr int HPS = 544;             // hpb bf16 row stride

// ---- workspace layout (float offsets) ----
constexpr size_t o_cb    = 0;                                   // NG*160 ushort
constexpr size_t o_q     = o_cb  + (size_t)NG * CBS / 2;        // H*NG*K fp32
constexpr size_t o_k     = o_q   + (size_t)H_ * NG * K_;
constexpr size_t o_wqk   = o_k   + (size_t)H_ * NG * K_;        // H*32*160 ushort
constexpr size_t o_wvt   = o_wqk + (size_t)H_ * 32 * CBS / 2;   // H*144*160 ushort
constexpr size_t o_vT    = o_wvt + (size_t)H_ * VTN * CBS / 2;  // H*144*NG ushort
constexpr size_t o_hpb   = o_vT  + (size_t)H_ * VTN * NG / 2;   // M*544 ushort
constexpr size_t o_cpost = o_hpb + (size_t)M_ * HPS / 2;        // M*CP fp32
constexpr size_t o_W1T   = o_cpost + (size_t)M_ * CP;           // 144*544 ushort
constexpr size_t o_W2T   = o_W1T + (size_t)144 * HPS / 2;       // 144*160 ushort
constexpr size_t o_wtru  = o_W2T + (size_t)144 * 160 / 2;       // 128*KT ushort
constexpr size_t o_wtc   = o_wtru + (size_t)128 * KT / 2;       // 64*KT ushort
constexpr size_t o_A     = o_wtc + (size_t)64 * KT / 2;         // M*KT ushort
constexpr size_t o_pru   = o_A + (size_t)M_ * KT / 2;           // 4*M*128 fp32
constexpr size_t o_pc2   = o_pru + (size_t)4 * M_ * 128;        // 4*M*64 fp32
// aliases: cin overlays q (spills into k; both dead post-attn)
constexpr size_t o_cin = o_q;      // M*CP

DEVINL float4 ld4(const float* p) { return *reinterpret_cast<const float4*>(p); }
DEVINL void st4(float* p, float4 v) { *reinterpret_cast<float4*>(p) = v; }
DEVINL ushort_t f2bf(float f) {           // RNE fp32->bf16
    unsigned int u = __float_as_uint(f);
    u += 0x7FFFu + ((u >> 16) & 1u);
    return (ushort_t)(u >> 16);
}

// ---------------- K0: build cb[NG][160] bf16 = [x | h | 1.0 | 0pad] ----------------
__global__ void k_comb(const float* __restrict__ x, const float* __restrict__ h,
                       ushort_t* __restrict__ cb) {
    int idx = blockIdx.x * 256 + threadIdx.x;
    if (idx >= NG * CBS) return;
    int g = idx / CBS, kk = idx - g * CBS;
    float v;
    if (kk < 65) v = x[g * 65 + kk];
    else if (kk < 129) v = h[g * 64 + (kk - 65)];
    else if (kk == 129) v = 1.0f;
    else v = 0.f;
    cb[idx] = f2bf(v);
}

// ---------------- K0a: build Wqk[H][32][160], Wvt[H][144][160] bf16 ----------------
__global__ void k_wqkv(const float* __restrict__ Wq, const float* __restrict__ bq,
                       const float* __restrict__ Wk, const float* __restrict__ bk,
                       const float* __restrict__ Wv, const float* __restrict__ bv,
                       ushort_t* __restrict__ wqk, ushort_t* __restrict__ wvt) {
    int idx = blockIdx.x * 256 + threadIdx.x;
    const int tot1 = H_ * 32 * CBS;
    const int tot2 = H_ * VTN * CBS;
    if (idx < tot1) {
        int hh = idx / (32 * CBS); int rem = idx - hh * 32 * CBS;
        int o = rem / CBS, kk = rem - o * CBS;
        float v = 0.f;
        if (o < 16) {
            if (kk < 129) v = Wq[(size_t)(hh * C_ + kk) * K_ + o];
            else if (kk == 129) v = bq[hh * K_ + o];
        } else {
            int o2 = o - 16;
            if (kk < 129) v = Wk[(size_t)(hh * C_ + kk) * K_ + o2];
            else if (kk == 129) v = bk[hh * K_ + o2];
        }
        wqk[idx] = f2bf(v);
    } else if (idx < tot1 + tot2) {
        int j = idx - tot1;
        int hh = j / (VTN * CBS); int rem = j - hh * VTN * CBS;
        int n = rem / CBS, kk = rem - n * CBS;
        float v = 0.f;
        if (n < C_) {
            if (kk < 129) v = Wv[(size_t)(hh * C_ + kk) * C_ + n];
            else if (kk == 129) v = bv[hh * C_ + n];
        }
        wvt[j] = f2bf(v);
    }
}

// ---------------- K0b: build W1T[144][544], W2T[144][160] bf16 ----------------
__global__ void k_wmlp(const float* __restrict__ W1, const float* __restrict__ W2,
                       ushort_t* __restrict__ W1T, ushort_t* __restrict__ W2T) {
    int idx = blockIdx.x * 256 + threadIdx.x;
    const int tot1 = 144 * HPS;
    const int tot2 = 144 * 160;
    if (idx < tot1) {
        int o = idx / HPS, k = idx - o * HPS;
        float v = (o < C_ && k < 516) ? W1[(size_t)k * C_ + o] : 0.f;
        W1T[idx] = f2bf(v);
    } else if (idx < tot1 + tot2) {
        int j = idx - tot1;
        int o = j / 160, k = j - o * 160;
        float v = (o < C_ && k < C_) ? W2[(size_t)k * C_ + o] : 0.f;
        W2T[j] = f2bf(v);
    }
}

// ---------------- K0c: build WT_ru[128][KT], WT_c[64][KT] bf16 ----------------
__global__ void k_wt(const float* __restrict__ Wr, const float* __restrict__ br,
                     const float* __restrict__ Wu, const float* __restrict__ bu,
                     const float* __restrict__ Wc, const float* __restrict__ bc,
                     ushort_t* __restrict__ wtru, ushort_t* __restrict__ wtc) {
    int idx = blockIdx.x * 256 + threadIdx.x;
    const int tot = 192 * KT;
    if (idx >= tot) return;
    int row = idx / KT, k = idx - row * KT;
    float v;
    if (k >= 4224) {
        int d = k - 4224;
        if (row < 64) v = br[d * 64 + row];
        else if (row < 128) v = bu[d * 64 + row - 64];
        else v = bc[d * 64 + row - 128];
    } else {
        int d = k / 132, i = k - d * 132;
        if (i >= 129) v = 0.f;
        else if (row < 64) v = Wr[(size_t)(d * 129 + i) * 64 + row];
        else if (row < 128) v = Wu[(size_t)(d * 129 + i) * 64 + row - 64];
        else v = Wc[(size_t)(d * 129 + i) * 64 + row - 128];
    }
    if (row < 128) wtru[(size_t)row * KT + k] = f2bf(v);
    else wtc[(size_t)(row - 128) * KT + k] = f2bf(v);
}

// ---------------- K1: MFMA projections: q,k fp32 + vT bf16 (transposed directly) ----------------
// grid (NG/16, H). 11 units: u0=q, u1=k (A=cb,B=Wqk); u2..10 = v tiles (A=Wvt,B=cb).
__global__ __launch_bounds__(256) void k_qkv(
    const ushort_t* __restrict__ cb, const ushort_t* __restrict__ wqk,
    const ushort_t* __restrict__ wvt,
    float* __restrict__ qo, float* __restrict__ ko, ushort_t* __restrict__ vTg) {
    const int t = threadIdx.x;
    const int g0 = blockIdx.x * 16;
    const int hh = blockIdx.y;
    const int lane = t & 63, w = t >> 6;
    const int am = lane & 15, aq = lane >> 4;
    short8 cbf[5];
    const ushort_t* Cr = cb + (size_t)(g0 + am) * CBS + aq * 8;
#pragma unroll
    for (int kt = 0; kt < 5; ++kt)
        cbf[kt] = *reinterpret_cast<const short8*>(Cr + kt * 32);
#pragma unroll
    for (int s = 0; s < 3; ++s) {
        int u = w + 4 * s;
        if (u >= 11) break;
        f32x4 acc = f32x4{0.f, 0.f, 0.f, 0.f};
        if (u < 2) {
            const ushort_t* Bp = wqk + ((size_t)(hh * 32 + u * 16 + am)) * CBS + aq * 8;
#pragma unroll
            for (int kt = 0; kt < 5; ++kt)
                acc = __builtin_amdgcn_mfma_f32_16x16x32_bf16(
                    cbf[kt], *reinterpret_cast<const short8*>(Bp + kt * 32), acc, 0, 0, 0);
            float* dst = u ? ko : qo;
#pragma unroll
            for (int i = 0; i < 4; ++i)
                dst[(size_t)(hh * NG + g0 + aq * 4 + i) * K_ + am] = acc[i];
        } else {
            int vt = u - 2;
            const ushort_t* Ap = wvt + ((size_t)(hh * VTN + vt * 16 + am)) * CBS + aq * 8;
#pragma unroll
            for (int kt = 0; kt < 5; ++kt)
                acc = __builtin_amdgcn_mfma_f32_16x16x32_bf16(
                    *reinterpret_cast<const short8*>(Ap + kt * 32), cbf[kt], acc, 0, 0, 0);
#pragma unroll
            for (int i = 0; i < 4; ++i)
                vTg[(size_t)(hh * VTN + vt * 16 + aq * 4 + i) * NG + g0 + am] = f2bf(acc[i]);
        }
    }
}

// ---------------- K3: attention — scalar QK/softmax + MFMA bf16 PV -> hpb bf16 ----------------
__global__ __launch_bounds__(256) void k_attn(
    const float* __restrict__ qg, const float* __restrict__ kg,
    const ushort_t* __restrict__ vTg,
    const int* __restrict__ adj, const int* __restrict__ nodes_b, const int* __restrict__ nodes_n,
    ushort_t* __restrict__ hpb) {
    __shared__ alignas(16) float Ks[64 * 20];
    __shared__ alignas(16) ushort_t Vt[VTN * 72];
    __shared__ alignas(16) ushort_t Pb[16 * 72];
    __shared__ float Lrow[16];
    __shared__ int Nrow[16];
    const int t = threadIdx.x;
    const int m0 = blockIdx.x * 16;
    const int hh = blockIdx.y;
    const int b = nodes_b[m0];
    if (t < 16) Nrow[t] = nodes_n[m0 + t];
    __syncthreads();
    const int r = t >> 4, cl = t & 15;
    float qreg[16];
    {
        const float* qp = &qg[(size_t)(hh * NG + b * N_ + Nrow[r]) * K_];
#pragma unroll
        for (int w4 = 0; w4 < 16; w4 += 4) {
            float4 qq = ld4(qp + w4);
            qreg[w4] = qq.x; qreg[w4 + 1] = qq.y; qreg[w4 + 2] = qq.z; qreg[w4 + 3] = qq.w;
        }
    }
    const int* adjrow = &adj[(size_t)Nrow[r] * N_];
    const int lane = t & 63, w = t >> 6;
    const int am = lane & 15, aq = lane >> 4;
    f32x4 accv[5];
#pragma unroll
    for (int s = 0; s < 5; ++s) accv[s] = f32x4{0.f, 0.f, 0.f, 0.f};
    float lsum = 0.f;

    for (int ct = 0; ct < 16; ++ct) {
        const int c0 = ct * 64;
        __syncthreads();
        {
            int row = t >> 2, k4 = (t & 3) * 4;
            st4(&Ks[row * 20 + k4], ld4(&kg[(size_t)(hh * NG + b * N_ + c0 + row) * K_ + k4]));
        }
        for (int idx = t; idx < VTN * 8; idx += 256) {
            int n = idx >> 3, l8 = idx & 7;
            *reinterpret_cast<ushort8*>(&Vt[n * 72 + l8 * 8]) =
                *reinterpret_cast<const ushort8*>(&vTg[(size_t)(hh * VTN + n) * NG + b * N_ + c0 + l8 * 8]);
        }
        __syncthreads();
#pragma unroll
        for (int j = 0; j < 4; ++j) {
            int c = cl + 16 * j;
            const float* kc = &Ks[c * 20];
            float4 k0 = ld4(kc), k1 = ld4(kc + 4), k2 = ld4(kc + 8), k3 = ld4(kc + 12);
            float dot = qreg[0]*k0.x + qreg[1]*k0.y + qreg[2]*k0.z + qreg[3]*k0.w
                      + qreg[4]*k1.x + qreg[5]*k1.y + qreg[6]*k1.z + qreg[7]*k1.w
                      + qreg[8]*k2.x + qreg[9]*k2.y + qreg[10]*k2.z + qreg[11]*k2.w
                      + qreg[12]*k3.x + qreg[13]*k3.y + qreg[14]*k3.z + qreg[15]*k3.w;
            float s = dot * 0.25f;
            s = (s >= 0.f) ? s : 0.2f * s;
            float p = adjrow[c0 + c] ? __expf(s) : 0.f;
            lsum += p;
            Pb[r * 72 + c] = f2bf(p);
        }
        __syncthreads();
#pragma unroll
        for (int s = 0; s < 5; ++s) {
            int u = 4 * s + w;
            if (u < 18) {
                int nt = u >> 1, kh = u & 1;
                short8 af = *reinterpret_cast<const short8*>(&Pb[am * 72 + kh * 32 + aq * 8]);
                short8 bfr = *reinterpret_cast<const short8*>(&Vt[(nt * 16 + am) * 72 + kh * 32 + aq * 8]);
                accv[s] = __builtin_amdgcn_mfma_f32_16x16x32_bf16(af, bfr, accv[s], 0, 0, 0);
            }
        }
    }
    lsum += __shfl_xor(lsum, 1);
    lsum += __shfl_xor(lsum, 2);
    lsum += __shfl_xor(lsum, 4);
    lsum += __shfl_xor(lsum, 8);
    if (cl == 0) Lrow[r] = lsum;
    __syncthreads();
    float* Ored = reinterpret_cast<float*>(Vt);
    if (w & 1) {
#pragma unroll
        for (int s = 0; s < 5; ++s) {
            int u = 4 * s + w;
            if (u < 18) {
                int nt = u >> 1;
#pragma unroll
                for (int i = 0; i < 4; ++i)
                    Ored[(aq * 4 + i) * 160 + nt * 16 + am] = accv[s][i];
            }
        }
    }
    if (t < 16) Lrow[t] = (Lrow[t] > 0.f) ? 1.f / Lrow[t] : 0.f;
    __syncthreads();
    if (!(w & 1)) {
#pragma unroll
        for (int s = 0; s < 5; ++s) {
            int u = 4 * s + w;
            if (u < 18) {
                int nt = u >> 1;
                int col = nt * 16 + am;
                if (col < C_) {
#pragma unroll
                    for (int i = 0; i < 4; ++i) {
                        int row = aq * 4 + i;
                        float val = (accv[s][i] + Ored[row * 160 + col]) * Lrow[row];
                        hpb[(size_t)(m0 + row) * HPS + hh * C_ + col] = f2bf(val);
                    }
                }
            }
        }
    }
    if (hh == 3) {
        for (int idx = t; idx < 16 * 28; idx += 256) {
            int rr = idx / 28, cc = 516 + (idx - rr * 28);
            hpb[(size_t)(m0 + rr) * HPS + cc] = 0;
        }
    }
}

// ---------------- K4: node MLP (MFMA) + skip -> cpost[M][CP] ----------------
__global__ __launch_bounds__(256) void k_mlp(
    const ushort_t* __restrict__ hpb,
    const ushort_t* __restrict__ W1T, const float* __restrict__ b1,
    const ushort_t* __restrict__ W2T, const float* __restrict__ b2,
    const float* __restrict__ x, const float* __restrict__ h,
    const int* __restrict__ nb, const int* __restrict__ nn,
    float* __restrict__ cpost) {
    __shared__ alignas(16) ushort_t Hs[16 * 168];
    const int t = threadIdx.x;
    const int m0 = blockIdx.x * 16;
    const int lane = t & 63, w = t >> 6;
    const int am = lane & 15, aq = lane >> 4;
    f32x4 acc[3];
#pragma unroll
    for (int j = 0; j < 3; ++j) acc[j] = f32x4{0.f, 0.f, 0.f, 0.f};
    const ushort_t* Ar = hpb + (size_t)(m0 + am) * HPS;
    for (int kt = 0; kt < 17; ++kt) {
        short8 af = *reinterpret_cast<const short8*>(Ar + kt * 32 + aq * 8);
#pragma unroll
        for (int j = 0; j < 3; ++j) {
            int nt = w + 4 * j;
            if (nt < 9) {
                short8 bf = *reinterpret_cast<const short8*>(W1T + (size_t)(nt * 16 + am) * HPS + kt * 32 + aq * 8);
                acc[j] = __builtin_amdgcn_mfma_f32_16x16x32_bf16(af, bf, acc[j], 0, 0, 0);
            }
        }
    }
#pragma unroll
    for (int j = 0; j < 3; ++j) {
        int nt = w + 4 * j;
        if (nt < 9) {
            int col = nt * 16 + am;
            float bb = (col < C_) ? b1[col] : 0.f;
#pragma unroll
            for (int i = 0; i < 4; ++i) {
                int row = aq * 4 + i;
                float v = (col < C_) ? fmaxf(acc[j][i] + bb, 0.f) : 0.f;
                Hs[row * 168 + col] = f2bf(v);
            }
        }
    }
    { int row = t >> 4, cc = 144 + (t & 15); Hs[row * 168 + cc] = 0; }
    __syncthreads();
    f32x4 acc2[3];
#pragma unroll
    for (int j = 0; j < 3; ++j) acc2[j] = f32x4{0.f, 0.f, 0.f, 0.f};
    for (int kt = 0; kt < 5; ++kt) {
        short8 af = *reinterpret_cast<const short8*>(&Hs[am * 168 + kt * 32 + aq * 8]);
#pragma unroll
        for (int j = 0; j < 3; ++j) {
            int nt = w + 4 * j;
            if (nt < 9) {
                short8 bf = *reinterpret_cast<const short8*>(W2T + (size_t)(nt * 16 + am) * 160 + kt * 32 + aq * 8);
                acc2[j] = __builtin_amdgcn_mfma_f32_16x16x32_bf16(af, bf, acc2[j], 0, 0, 0);
            }
        }
    }
#pragma unroll
    for (int j = 0; j < 3; ++j) {
        int nt = w + 4 * j;
        if (nt < 9) {
            int col = nt * 16 + am;
            if (col < C_) {
                float bb = b2[col];
#pragma unroll
                for (int i = 0; i < 4; ++i) {
                    int m = m0 + aq * 4 + i;
                    int b = nb[m], n = nn[m];
                    float sk = (col < 65) ? x[(b * N_ + n) * 65 + col]
                                          : h[(b * N_ + n) * D_ + (col - 65)];
                    cpost[(size_t)m * CP + col] = acc2[j][i] + bb + sk;
                }
            }
        }
    }
    if (t < 48) {
        int rr = t / 3, cc = 129 + (t - (t / 3) * 3);
        cpost[(size_t)(m0 + rr) * CP + cc] = 0.f;
    }
}

// ---------------- K5a: build A[m][KT] bf16 ----------------
__global__ __launch_bounds__(256) void k_arow(const float* __restrict__ src,
                                              const float* __restrict__ qv,
                                              ushort_t* __restrict__ A) {
    __shared__ float sq[CP];
    __shared__ float qs[QV_];
    const int t = threadIdx.x;
    const int m = blockIdx.x;
    if (t < CP) sq[t] = src[(size_t)m * CP + t];
    if (t >= 224) qs[t - 224] = qv[m * QV_ + (t - 224)];
    __syncthreads();
    ushort_t* Ar = A + (size_t)m * KT;
    for (int k = t; k < 4224; k += 256) {
        int d = k / 132, i = k - d * 132;
        Ar[k] = f2bf(qs[d] * sq[i]);
    }
    if (t < QV_) Ar[4224 + t] = f2bf(qs[t]);
}

// ---------------- K5b: hyper GEMM part[z][M][NN] = A-chunk @ WT^T ----------------
template<int NN>
__global__ __launch_bounds__(256) void k_gemm(const ushort_t* __restrict__ A,
                                              const ushort_t* __restrict__ WT,
                                              float* __restrict__ part) {
    const int t = threadIdx.x;
    const int m0 = blockIdx.x * 16;
    const int z = blockIdx.y;
    const int lane = t & 63, w = t >> 6;
    const int am = lane & 15, aq = lane >> 4;
    constexpr int NTpW = NN / 64;
    const int ktb = z * 34;
    const int kte = (ktb + 34 < NKT) ? ktb + 34 : NKT;
    f32x4 acc[NTpW];
#pragma unroll
    for (int j = 0; j < NTpW; ++j) acc[j] = f32x4{0.f, 0.f, 0.f, 0.f};
    const ushort_t* Ar = A + (size_t)(m0 + am) * KT;
    for (int kt = ktb; kt < kte; ++kt) {
        const int ko = kt * 32 + aq * 8;
        short8 af = *reinterpret_cast<const short8*>(Ar + ko);
#pragma unroll
        for (int j = 0; j < NTpW; ++j) {
            int nt = w + 4 * j;
            short8 bf = *reinterpret_cast<const short8*>(WT + (size_t)(nt * 16 + am) * KT + ko);
            acc[j] = __builtin_amdgcn_mfma_f32_16x16x32_bf16(af, bf, acc[j], 0, 0, 0);
        }
    }
#pragma unroll
    for (int j = 0; j < NTpW; ++j) {
        int n = (w + 4 * j) * 16 + am;
#pragma unroll
        for (int i = 0; i < 4; ++i) {
            int m = m0 + aq * 4 + i;
            part[((size_t)z * M_ + m) * NN + n] = acc[j][i];
        }
    }
}

// ---------------- K5c: build cin[M][CP] ----------------
__global__ void k_build_cin(const float* __restrict__ x, const float* __restrict__ h,
                            const int* __restrict__ nb, const int* __restrict__ nn,
                            const float* __restrict__ pru, float* __restrict__ cin) {
    int idx = blockIdx.x * 256 + threadIdx.x;
    if (idx >= M_ * CP) return;
    int m = idx / CP, i = idx - m * CP;
    int b = nb[m], n = nn[m];
    float val;
    if (i < 65) val = x[(b * N_ + n) * 65 + i];
    else if (i < C_) {
        int o = i - 65;
        const size_t S = (size_t)M_ * 128;
        size_t base = (size_t)m * 128 + o;
        float s = pru[base] + pru[S + base] + pru[2 * S + base] + pru[3 * S + base];
        float rv = 1.f / (1.f + __expf(-s));
        val = rv * h[(b * N_ + n) * D_ + o];
    } else val = 0.f;
    cin[idx] = val;
}

// ---------------- K5d: final gate ----------------
__global__ void k_final(const float* __restrict__ pru, const float* __restrict__ pc,
                        const float* __restrict__ cin, float* __restrict__ out) {
    int idx = blockIdx.x * 256 + threadIdx.x;
    if (idx >= M_ * D_) return;
    int m = idx >> 6, o = idx & 63;
    const size_t Su = (size_t)M_ * 128;
    size_t bu = (size_t)m * 128 + 64 + o;
    float su = pru[bu] + pru[Su + bu] + pru[2 * Su + bu] + pru[3 * Su + bu];
    float uv = 1.f / (1.f + __expf(-su));
    const size_t Sc = (size_t)M_ * 64;
    size_t bc = (size_t)m * 64 + o;
    float sc = pc[bc] + pc[Sc + bc] + pc[2 * Sc + bc] + pc[3 * Sc + bc];
    float cand = tanhf(sc);
    float hn = cin[(size_t)m * CP + 65 + o];
    out[idx] = (1.f - uv) * hn + uv * cand;
}

extern "C" void kernel_launch(void* const* d_in, const int* in_sizes, int n_in,
                              void* d_out, int out_size, void* d_ws, size_t ws_size,
                              hipStream_t stream) {
    const float* x   = (const float*)d_in[0];
    const float* h   = (const float*)d_in[1];
    const float* qv  = (const float*)d_in[2];
    const int*   adj = (const int*)d_in[3];
    const int*   nb  = (const int*)d_in[4];
    const int*   nn  = (const int*)d_in[5];
    const float* Wq  = (const float*)d_in[6];
    const float* bq  = (const float*)d_in[7];
    const float* Wk  = (const float*)d_in[8];
    const float* bk  = (const float*)d_in[9];
    const float* Wv  = (const float*)d_in[10];
    const float* bv  = (const float*)d_in[11];
    const float* W1  = (const float*)d_in[12];
    const float* b1  = (const float*)d_in[13];
    const float* W2  = (const float*)d_in[14];
    const float* b2  = (const float*)d_in[15];
    const float* Wr  = (const float*)d_in[16];
    const float* br  = (const float*)d_in[17];
    const float* Wu  = (const float*)d_in[18];
    const float* bu  = (const float*)d_in[19];
    const float* Wc  = (const float*)d_in[20];
    const float* bc  = (const float*)d_in[21];
    float* ws = (float*)d_ws;
    float* out = (float*)d_out;

    ushort_t* cb   = (ushort_t*)(ws + o_cb);
    float* qo    = ws + o_q;
    float* ko    = ws + o_k;
    ushort_t* wqk  = (ushort_t*)(ws + o_wqk);
    ushort_t* wvt  = (ushort_t*)(ws + o_wvt);
    ushort_t* vTg  = (ushort_t*)(ws + o_vT);
    ushort_t* hpb  = (ushort_t*)(ws + o_hpb);
    float* cpost = ws + o_cpost;
    ushort_t* W1T  = (ushort_t*)(ws + o_W1T);
    ushort_t* W2T  = (ushort_t*)(ws + o_W2T);
    ushort_t* wtru = (ushort_t*)(ws + o_wtru);
    ushort_t* wtc  = (ushort_t*)(ws + o_wtc);
    ushort_t* Abuf = (ushort_t*)(ws + o_A);
    float* pru   = ws + o_pru;
    float* pc    = ws + o_pc2;
    float* cin   = ws + o_cin;

    k_comb<<<(NG * CBS + 255) / 256, 256, 0, stream>>>(x, h, cb);
    k_wqkv<<<(H_ * 32 * CBS + H_ * VTN * CBS + 255) / 256, 256, 0, stream>>>(
        Wq, bq, Wk, bk, Wv, bv, wqk, wvt);
    k_wmlp<<<(144 * HPS + 144 * 160 + 255) / 256, 256, 0, stream>>>(W1, W2, W1T, W2T);
    k_wt<<<(192 * KT + 255) / 256, 256, 0, stream>>>(Wr, br, Wu, bu, Wc, bc, wtru, wtc);
    k_qkv<<<dim3(NG / 16, H_), 256, 0, stream>>>(cb, wqk, wvt, qo, ko, vTg);
    k_attn<<<dim3(M_ / 16, H_), 256, 0, stream>>>(qo, ko, vTg, adj, nb, nn, hpb);
    k_mlp<<<M_ / 16, 256, 0, stream>>>(hpb, W1T, b1, W2T, b2, x, h, nb, nn, cpost);
    k_arow<<<M_, 256, 0, stream>>>(cpost, qv, Abuf);
    k_gemm<128><<<dim3(M_ / 16, 4), 256, 0, stream>>>(Abuf, wtru, pru);
    k_build_cin<<<(M_ * CP) / 256, 256, 0, stream>>>(x, h, nb, nn, pru, cin);
    k_arow<<<M_, 256, 0, stream>>>(cin, qv, Abuf);
    k_gemm<64><<<dim3(M_ / 16, 4), 256, 0, stream>>>(Abuf, wtc, pc);
    k_final<<<(M_ * D_) / 256, 256, 0, stream>>>(pru, pc, cin, out);
}